// Round 2
// baseline (2530.462 us; speedup 1.0000x reference)
//
#include <hip/hip_runtime.h>
#include <cstddef>

#define NEG_SLOPE 0.2f

__device__ __forceinline__ float leaky(float v) { return v >= 0.f ? v : NEG_SLOPE * v; }
__device__ __forceinline__ void atomAdd(float* p, float v) { unsafeAtomicAdd(p, v); }

// ---------- tiny per-relation constants + attention-vector projections ----------
// relfeat[r*128+h*32+d]; wes/wed[r*512+h*128+c]; ces/ced[r*4+h]
__global__ void k_small(const float* __restrict__ rel_emb, const float* __restrict__ W_relT,
                        const float* __restrict__ W_relprop, const float* __restrict__ b_relprop,
                        const float* __restrict__ W_fuse, const float* __restrict__ W_src,
                        const float* __restrict__ b_src, const float* __restrict__ W_node,
                        const float* __restrict__ b_node,
                        float* __restrict__ relfeat, float* __restrict__ wes, float* __restrict__ wed,
                        float* __restrict__ ces, float* __restrict__ ced) {
    __shared__ float av[512];     // attn vectors [r][h][i][d]
    __shared__ float rp[2][128];  // rel_prop
    int t = threadIdx.x;  // 512 threads
    {
        int r = t >> 8, m = t & 255;
        float acc = 0.f;
        const float* re = rel_emb + r * 64;
        const float* w = W_relT + (size_t)r * 16384 + m;
        #pragma unroll 8
        for (int k = 0; k < 64; ++k) acc += re[k] * w[(size_t)k * 256];
        av[t] = acc;
    }
    if (t < 256) {
        int r = t >> 7, m = t & 127;
        float acc = b_relprop[t];
        const float* re = rel_emb + r * 64;
        const float* w = W_relprop + (size_t)r * 8192 + m;
        #pragma unroll 8
        for (int k = 0; k < 64; ++k) acc += re[k] * w[(size_t)k * 128];
        rp[r][m] = acc;
    }
    __syncthreads();
    if (t < 256) {  // relation fusing feature
        int r = t >> 7, h = (t >> 5) & 3, d = t & 31;
        float acc = 0.f;
        const float* w = W_fuse + ((size_t)(r * 4 + h) * 32) * 32 + d;
        #pragma unroll
        for (int k = 0; k < 32; ++k) acc += rp[r][h * 32 + k] * w[(size_t)k * 32];
        relfeat[t] = acc;
    }
    // project attn vectors through weights: wes[r][h] = W_src[r][:,h*32:+32] @ a_src,
    // wed[r][h] = W_node[:,h*32:+32] @ a_dst  (so scores come straight from x)
    for (int idx = t; idx < 2048; idx += 512) {
        int which = idx >> 10, rem = idx & 1023;
        int r = rem >> 9, h = (rem >> 7) & 3, c = rem & 127;
        const float* W = which ? W_node : (W_src + (size_t)r * 16384);
        const float* a = av + r * 256 + h * 64 + which * 32;
        float acc = 0.f;
        #pragma unroll
        for (int d = 0; d < 32; ++d) acc += W[(size_t)c * 128 + h * 32 + d] * a[d];
        (which ? wed : wes)[rem] = acc;
    }
    if (t < 16) {
        int which = t >> 3, r = (t >> 2) & 1, h = t & 3;
        const float* b = which ? b_node : (b_src + r * 128);
        const float* a = av + r * 256 + h * 64 + which * 32;
        float acc = 0.f;
        #pragma unroll
        for (int d = 0; d < 32; ++d) acc += b[h * 32 + d] * a[d];
        (which ? ced : ces)[r * 4 + h] = acc;
    }
}

// ---------- degrees ----------
__global__ void k_degree(const int* __restrict__ src, const int* __restrict__ dst,
                         float* __restrict__ dego, float* __restrict__ degi, int n) {
    int i = blockIdx.x * blockDim.x + threadIdx.x;
    if (i < n) {
        atomAdd(dego + src[i], 1.f);
        atomAdd(degi + dst[i], 1.f);
    }
}

__global__ void k_rs(float* __restrict__ v, int n) {
    int i = blockIdx.x * blockDim.x + threadIdx.x;
    if (i < n) v[i] = rsqrtf(fmaxf(v[i], 1.f));
}

// ---------- per-node attention scores from x directly (skinny GEMM N x 128 x 16) ----------
__global__ __launch_bounds__(256) void k_nodescore(const float* __restrict__ x,
                                                   const float* __restrict__ wes, const float* __restrict__ wed,
                                                   const float* __restrict__ ces, const float* __restrict__ ced,
                                                   float* __restrict__ es0, float* __restrict__ es1,
                                                   float* __restrict__ ed0, float* __restrict__ ed1, int n) {
    __shared__ float xs[64 * 132];  // +4 pad: bank-conflict break
    int tid = threadIdx.x;
    int nb0 = blockIdx.x * 64;
    for (int i = tid; i < 64 * 32; i += 256) {
        int row = i >> 5, c4 = i & 31;
        float4 v = make_float4(0.f, 0.f, 0.f, 0.f);
        if (nb0 + row < n) v = *(const float4*)(x + (size_t)(nb0 + row) * 128 + c4 * 4);
        *(float4*)(xs + row * 132 + c4 * 4) = v;
    }
    __syncthreads();
    int node = tid >> 2;
    int gn = nb0 + node;
    if (gn >= n) return;
    #pragma unroll
    for (int q = 0; q < 4; ++q) {
        int j = (tid & 3) + q * 4;          // j = which*8 + r*4 + h
        int which = j >> 3, r = (j >> 2) & 1, h = j & 3;
        const float* w = (which ? wed : wes) + r * 512 + h * 128;
        float acc = (which ? ced : ces)[r * 4 + h];
        #pragma unroll 16
        for (int d = 0; d < 128; ++d) acc += xs[node * 132 + d] * w[d];
        float* outp = which ? (r ? ed1 : ed0) : (r ? es1 : es0);
        outp[(size_t)gn * 4 + h] = acc;
    }
}

// ---------- 128x128 GEMM, tile 64 nodes: Y = X@W + b ----------
__global__ __launch_bounds__(256) void k_gemm(const float* __restrict__ X, const float* __restrict__ W,
                                              const float* __restrict__ bias, float* __restrict__ Y, int n) {
    __shared__ float xs[64 * 128];
    __shared__ float wc[32 * 128];
    int tid = threadIdx.x;
    int nb0 = blockIdx.x * 64;
    for (int i = tid; i < 64 * 32; i += 256) {
        int row = i >> 5, c4 = i & 31;
        float4 v = make_float4(0.f, 0.f, 0.f, 0.f);
        if (nb0 + row < n) v = *(const float4*)(X + (size_t)(nb0 + row) * 128 + c4 * 4);
        *(float4*)(xs + row * 128 + c4 * 4) = v;
    }
    float acc[8][4];
    #pragma unroll
    for (int i = 0; i < 8; ++i)
        #pragma unroll
        for (int c = 0; c < 4; ++c) acc[i][c] = 0.f;
    int col4 = (tid & 31) * 4;
    int r0 = (tid >> 5) * 8;
    for (int kc = 0; kc < 4; ++kc) {
        __syncthreads();
        for (int i = tid; i < 32 * 32; i += 256) {
            int kk = i >> 5, c4 = i & 31;
            *(float4*)(wc + kk * 128 + c4 * 4) = *(const float4*)(W + (size_t)(kc * 32 + kk) * 128 + c4 * 4);
        }
        __syncthreads();
        #pragma unroll
        for (int kk = 0; kk < 32; ++kk) {
            float4 w = *(const float4*)(wc + kk * 128 + col4);
            #pragma unroll
            for (int i = 0; i < 8; ++i) {
                float xv = xs[(r0 + i) * 128 + kc * 32 + kk];
                acc[i][0] += xv * w.x; acc[i][1] += xv * w.y;
                acc[i][2] += xv * w.z; acc[i][3] += xv * w.w;
            }
        }
    }
    float4 b = *(const float4*)(bias + col4);
    #pragma unroll
    for (int i = 0; i < 8; ++i) {
        int row = nb0 + r0 + i;
        if (row < n) {
            float4 o = make_float4(acc[i][0] + b.x, acc[i][1] + b.y, acc[i][2] + b.z, acc[i][3] + b.w);
            *(float4*)(Y + (size_t)row * 128 + col4) = o;
        }
    }
}

// ---------- per-relation edge aggregation: U[dst] += exp(e)*fs[src]; hg[dst] += x[src]*rsdo[src];
// ---------- sd[dst,h] += exp(e)  (fused softmax denominator; no max-subtract, |e| < ~10) ----------
__global__ __launch_bounds__(256) void k_edgeagg(const int* __restrict__ src, const int* __restrict__ dst,
                                                 const float* __restrict__ x, const float* __restrict__ rsdo,
                                                 const float* __restrict__ fs,
                                                 const float* __restrict__ es, const float* __restrict__ ed,
                                                 float* __restrict__ U, float* __restrict__ sd,
                                                 float* __restrict__ hg, int E) {
    int e = blockIdx.x * 2 + (threadIdx.x >> 7);
    int j = threadIdx.x & 127;
    if (e >= E) return;
    int s = src[e], d = dst[e];
    int h = j >> 5;
    float ex = __expf(leaky(es[(size_t)s * 4 + h] + ed[(size_t)d * 4 + h]));
    if ((j & 31) == 0) atomAdd(sd + (size_t)d * 4 + h, ex);
    atomAdd(U + (size_t)d * 128 + j, ex * fs[(size_t)s * 128 + j]);
    atomAdd(hg + (size_t)d * 128 + j, x[(size_t)s * 128 + j] * rsdo[s]);
}

// ---------- relation-fusion softmax weights ----------
__global__ void k_scores(const float* __restrict__ U0, const float* __restrict__ U1,
                         const float* __restrict__ sd0, const float* __restrict__ sd1,
                         const float* __restrict__ relfeat,
                         float* __restrict__ ar0, float* __restrict__ ar1, int n) {
    int idx = blockIdx.x * 256 + threadIdx.x;
    if (idx >= n * 4) return;
    int nn = idx >> 2, h = idx & 3;
    float is0 = 1.f / (sd0[idx] + 1e-9f);
    float is1 = 1.f / (sd1[idx] + 1e-9f);
    const float* u0 = U0 + (size_t)nn * 128 + h * 32;
    const float* u1 = U1 + (size_t)nn * 128 + h * 32;
    const float* rf0 = relfeat + h * 32;
    const float* rf1 = relfeat + 128 + h * 32;
    float sc0 = 0.f, sc1 = 0.f;
    #pragma unroll
    for (int d = 0; d < 32; ++d) {
        sc0 += fmaxf(u0[d] * is0, 0.f) * rf0[d];
        sc1 += fmaxf(u1[d] * is1, 0.f) * rf1[d];
    }
    sc0 = leaky(sc0); sc1 = leaky(sc1);
    float m = fmaxf(sc0, sc1);
    float p0 = __expf(sc0 - m), p1 = __expf(sc1 - m);
    float inv = 1.f / (p0 + p1);
    ar0[idx] = p0 * inv;
    ar1[idx] = p1 * inv;
}

// ---------- final: node_level GEMM (hg-in-out * rsdi @ W_g) + feat_dst GEMM (x @ W_node) + epilogue ----------
__global__ __launch_bounds__(256) void k_final(const float* __restrict__ x,
                                               const float* __restrict__ Wn, const float* __restrict__ bn,
                                               const float* __restrict__ Wg, const float* __restrict__ bg,
                                               const float* __restrict__ rsdi,
                                               const float* __restrict__ U0, const float* __restrict__ U1,
                                               const float* __restrict__ sd0, const float* __restrict__ sd1,
                                               const float* __restrict__ ar0, const float* __restrict__ ar1,
                                               const float* __restrict__ residual_w, const float* __restrict__ scale_w,
                                               float* __restrict__ out, int n) {
    __shared__ float xs[64 * 128];
    __shared__ float wc[32 * 128];
    int tid = threadIdx.x;
    int nb0 = blockIdx.x * 64;
    int col4 = (tid & 31) * 4;
    int r0 = (tid >> 5) * 8;
    float accg[8][4], accn[8][4];

    // ---- phase A: node_level pre-activation = (hg * rsdi) @ Wg ----
    for (int i = tid; i < 64 * 32; i += 256) {
        int row = i >> 5, c4 = i & 31;
        float4 v = make_float4(0.f, 0.f, 0.f, 0.f);
        if (nb0 + row < n) {
            float sc = rsdi[nb0 + row];
            v = *(const float4*)(out + (size_t)(nb0 + row) * 128 + c4 * 4);
            v.x *= sc; v.y *= sc; v.z *= sc; v.w *= sc;
        }
        *(float4*)(xs + row * 128 + c4 * 4) = v;
    }
    #pragma unroll
    for (int i = 0; i < 8; ++i)
        #pragma unroll
        for (int c = 0; c < 4; ++c) accg[i][c] = 0.f;
    for (int kc = 0; kc < 4; ++kc) {
        __syncthreads();
        for (int i = tid; i < 32 * 32; i += 256) {
            int kk = i >> 5, c4 = i & 31;
            *(float4*)(wc + kk * 128 + c4 * 4) = *(const float4*)(Wg + (size_t)(kc * 32 + kk) * 128 + c4 * 4);
        }
        __syncthreads();
        #pragma unroll
        for (int kk = 0; kk < 32; ++kk) {
            float4 w = *(const float4*)(wc + kk * 128 + col4);
            #pragma unroll
            for (int i = 0; i < 8; ++i) {
                float xv = xs[(r0 + i) * 128 + kc * 32 + kk];
                accg[i][0] += xv * w.x; accg[i][1] += xv * w.y;
                accg[i][2] += xv * w.z; accg[i][3] += xv * w.w;
            }
        }
    }
    __syncthreads();

    // ---- phase B: feat_dst pre-bias = x @ Wn ----
    for (int i = tid; i < 64 * 32; i += 256) {
        int row = i >> 5, c4 = i & 31;
        float4 v = make_float4(0.f, 0.f, 0.f, 0.f);
        if (nb0 + row < n) v = *(const float4*)(x + (size_t)(nb0 + row) * 128 + c4 * 4);
        *(float4*)(xs + row * 128 + c4 * 4) = v;
    }
    #pragma unroll
    for (int i = 0; i < 8; ++i)
        #pragma unroll
        for (int c = 0; c < 4; ++c) accn[i][c] = 0.f;
    for (int kc = 0; kc < 4; ++kc) {
        __syncthreads();
        for (int i = tid; i < 32 * 32; i += 256) {
            int kk = i >> 5, c4 = i & 31;
            *(float4*)(wc + kk * 128 + c4 * 4) = *(const float4*)(Wn + (size_t)(kc * 32 + kk) * 128 + c4 * 4);
        }
        __syncthreads();
        #pragma unroll
        for (int kk = 0; kk < 32; ++kk) {
            float4 w = *(const float4*)(wc + kk * 128 + col4);
            #pragma unroll
            for (int i = 0; i < 8; ++i) {
                float xv = xs[(r0 + i) * 128 + kc * 32 + kk];
                accn[i][0] += xv * w.x; accn[i][1] += xv * w.y;
                accn[i][2] += xv * w.z; accn[i][3] += xv * w.w;
            }
        }
    }

    // ---- epilogue ----
    float beta = 1.f / (1.f + __expf(-residual_w[0]));
    float av = 1.f / (1.f + __expf(-scale_w[0]));
    float4 bgv = *(const float4*)(bg + col4);
    float4 bnv = *(const float4*)(bn + col4);
    int h = col4 >> 5;
    #pragma unroll
    for (int i = 0; i < 8; ++i) {
        int row = nb0 + r0 + i;
        if (row < n) {
            float is0 = 1.f / (sd0[(size_t)row * 4 + h] + 1e-9f);
            float is1 = 1.f / (sd1[(size_t)row * 4 + h] + 1e-9f);
            float a0 = ar0[(size_t)row * 4 + h];
            float a1 = ar1[(size_t)row * 4 + h];
            float4 u0 = *(const float4*)(U0 + (size_t)row * 128 + col4);
            float4 u1 = *(const float4*)(U1 + (size_t)row * 128 + col4);
            float4 o;
            float f0, f1, fu, nl, fd;
            f0 = fmaxf(u0.x * is0, 0.f); f1 = fmaxf(u1.x * is1, 0.f);
            fd = accn[i][0] + bnv.x;
            fu = beta * (a0 * f0 + a1 * f1) + (1.f - beta) * fd;
            nl = fmaxf(accg[i][0] + bgv.x, 0.f);
            o.x = av * fu + (1.f - av) * nl;
            f0 = fmaxf(u0.y * is0, 0.f); f1 = fmaxf(u1.y * is1, 0.f);
            fd = accn[i][1] + bnv.y;
            fu = beta * (a0 * f0 + a1 * f1) + (1.f - beta) * fd;
            nl = fmaxf(accg[i][1] + bgv.y, 0.f);
            o.y = av * fu + (1.f - av) * nl;
            f0 = fmaxf(u0.z * is0, 0.f); f1 = fmaxf(u1.z * is1, 0.f);
            fd = accn[i][2] + bnv.z;
            fu = beta * (a0 * f0 + a1 * f1) + (1.f - beta) * fd;
            nl = fmaxf(accg[i][2] + bgv.z, 0.f);
            o.z = av * fu + (1.f - av) * nl;
            f0 = fmaxf(u0.w * is0, 0.f); f1 = fmaxf(u1.w * is1, 0.f);
            fd = accn[i][3] + bnv.w;
            fu = beta * (a0 * f0 + a1 * f1) + (1.f - beta) * fd;
            nl = fmaxf(accg[i][3] + bgv.w, 0.f);
            o.w = av * fu + (1.f - av) * nl;
            *(float4*)(out + (size_t)row * 128 + col4) = o;
        }
    }
}

extern "C" void kernel_launch(void* const* d_in, const int* in_sizes, int n_in,
                              void* d_out, int out_size, void* d_ws, size_t ws_size,
                              hipStream_t stream) {
    const float* x         = (const float*)d_in[0];
    const int*   src       = (const int*)d_in[1];
    const int*   dst       = (const int*)d_in[2];
    const float* rel_emb   = (const float*)d_in[3];
    const float* W_node    = (const float*)d_in[4];
    const float* b_node    = (const float*)d_in[5];
    const float* W_src     = (const float*)d_in[6];
    const float* b_src     = (const float*)d_in[7];
    const float* W_relT    = (const float*)d_in[8];
    const float* W_relprop = (const float*)d_in[9];
    const float* b_relprop = (const float*)d_in[10];
    const float* W_fuse    = (const float*)d_in[11];
    const float* resid_w   = (const float*)d_in[12];
    const float* scale_w   = (const float*)d_in[13];
    const float* W_g       = (const float*)d_in[14];
    const float* b_g       = (const float*)d_in[15];
    float* out = (float*)d_out;

    const int N = in_sizes[0] / 128;
    const int RE = in_sizes[1];
    const int E = RE / 2;

    // workspace layout (floats): total 418*N + 2848  (~167 MB at N=1e5)
    float* ws = (float*)d_ws;
    size_t o = 0;
    float* U0   = ws + o; o += (size_t)N * 128;  // zero region start
    float* U1   = ws + o; o += (size_t)N * 128;
    float* sd0  = ws + o; o += (size_t)N * 4;
    float* sd1  = ws + o; o += (size_t)N * 4;
    float* rsdo = ws + o; o += N;
    float* rsdi = ws + o; o += N;                // zero region end (266*N floats)
    float* fs   = ws + o; o += (size_t)N * 128;  // reused per relation
    float* es0  = ws + o; o += (size_t)N * 4;
    float* es1  = ws + o; o += (size_t)N * 4;
    float* ed0  = ws + o; o += (size_t)N * 4;
    float* ed1  = ws + o; o += (size_t)N * 4;
    float* ar0  = ws + o; o += (size_t)N * 4;
    float* ar1  = ws + o; o += (size_t)N * 4;
    float* relfeat = ws + o; o += 256;
    float* wes  = ws + o; o += 1024;
    float* wed  = ws + o; o += 1024;
    float* ces  = ws + o; o += 16;
    float* ced  = ws + o; o += 16;

    hipMemsetAsync(U0, 0, sizeof(float) * (size_t)266 * N, stream);
    hipMemsetAsync(out, 0, sizeof(float) * (size_t)out_size, stream);  // hg accumulates here

    k_small<<<1, 512, 0, stream>>>(rel_emb, W_relT, W_relprop, b_relprop, W_fuse,
                                   W_src, b_src, W_node, b_node,
                                   relfeat, wes, wed, ces, ced);
    k_degree<<<(RE + 255) / 256, 256, 0, stream>>>(src, dst, rsdo, rsdi, RE);
    k_rs<<<(2 * N + 255) / 256, 256, 0, stream>>>(rsdo, 2 * N);

    dim3 ggrid((N + 63) / 64);
    k_nodescore<<<ggrid, 256, 0, stream>>>(x, wes, wed, ces, ced, es0, es1, ed0, ed1, N);

    // relation 0
    k_gemm<<<ggrid, 256, 0, stream>>>(x, W_src, b_src, fs, N);
    k_edgeagg<<<(E + 1) / 2, 256, 0, stream>>>(src, dst, x, rsdo, fs, es0, ed0, U0, sd0, out, E);
    // relation 1
    k_gemm<<<ggrid, 256, 0, stream>>>(x, W_src + 16384, b_src + 128, fs, N);
    k_edgeagg<<<(E + 1) / 2, 256, 0, stream>>>(src + E, dst + E, x, rsdo, fs, es1, ed1, U1, sd1, out, E);

    k_scores<<<(N * 4 + 255) / 256, 256, 0, stream>>>(U0, U1, sd0, sd1, relfeat, ar0, ar1, N);
    k_final<<<ggrid, 256, 0, stream>>>(x, W_node, b_node, W_g, b_g, rsdi,
                                       U0, U1, sd0, sd1, ar0, ar1, resid_w, scale_w, out, N);
}

// Round 3
// 1410.115 us; speedup vs baseline: 1.7945x; 1.7945x over previous
//
#include <hip/hip_runtime.h>
#include <cstddef>

#define NEG_SLOPE 0.2f

__device__ __forceinline__ float leaky(float v) { return v >= 0.f ? v : NEG_SLOPE * v; }
__device__ __forceinline__ void atomAdd(float* p, float v) { unsafeAtomicAdd(p, v); }

// ---------- tiny per-relation constants + attention-vector projections ----------
// relfeat[r*128+h*32+d]; wes/wed[r*512+h*128+c]; ces/ced[r*4+h]
__global__ void k_small(const float* __restrict__ rel_emb, const float* __restrict__ W_relT,
                        const float* __restrict__ W_relprop, const float* __restrict__ b_relprop,
                        const float* __restrict__ W_fuse, const float* __restrict__ W_src,
                        const float* __restrict__ b_src, const float* __restrict__ W_node,
                        const float* __restrict__ b_node,
                        float* __restrict__ relfeat, float* __restrict__ wes, float* __restrict__ wed,
                        float* __restrict__ ces, float* __restrict__ ced) {
    __shared__ float av[512];     // attn vectors [r][h][i][d]
    __shared__ float rp[2][128];  // rel_prop
    int t = threadIdx.x;  // 512 threads
    {
        int r = t >> 8, m = t & 255;
        float acc = 0.f;
        const float* re = rel_emb + r * 64;
        const float* w = W_relT + (size_t)r * 16384 + m;
        #pragma unroll 8
        for (int k = 0; k < 64; ++k) acc += re[k] * w[(size_t)k * 256];
        av[t] = acc;
    }
    if (t < 256) {
        int r = t >> 7, m = t & 127;
        float acc = b_relprop[t];
        const float* re = rel_emb + r * 64;
        const float* w = W_relprop + (size_t)r * 8192 + m;
        #pragma unroll 8
        for (int k = 0; k < 64; ++k) acc += re[k] * w[(size_t)k * 128];
        rp[r][m] = acc;
    }
    __syncthreads();
    if (t < 256) {  // relation fusing feature
        int r = t >> 7, h = (t >> 5) & 3, d = t & 31;
        float acc = 0.f;
        const float* w = W_fuse + ((size_t)(r * 4 + h) * 32) * 32 + d;
        #pragma unroll
        for (int k = 0; k < 32; ++k) acc += rp[r][h * 32 + k] * w[(size_t)k * 32];
        relfeat[t] = acc;
    }
    // project attn vectors through weights so edge scores come straight from x
    for (int idx = t; idx < 2048; idx += 512) {
        int which = idx >> 10, rem = idx & 1023;
        int r = rem >> 9, h = (rem >> 7) & 3, c = rem & 127;
        const float* W = which ? W_node : (W_src + (size_t)r * 16384);
        const float* a = av + r * 256 + h * 64 + which * 32;
        float acc = 0.f;
        #pragma unroll
        for (int d = 0; d < 32; ++d) acc += W[(size_t)c * 128 + h * 32 + d] * a[d];
        (which ? wed : wes)[rem] = acc;
    }
    if (t < 16) {
        int which = t >> 3, r = (t >> 2) & 1, h = t & 3;
        const float* b = which ? b_node : (b_src + r * 128);
        const float* a = av + r * 256 + h * 64 + which * 32;
        float acc = 0.f;
        #pragma unroll
        for (int d = 0; d < 32; ++d) acc += b[h * 32 + d] * a[d];
        (which ? ced : ces)[r * 4 + h] = acc;
    }
}

// ---------- degree histogram: float out-degree (homogenized) + per-relation int dst counts ----------
__global__ void k_degree(const int* __restrict__ src, const int* __restrict__ dst,
                         float* __restrict__ dego, int* __restrict__ cnt0, int* __restrict__ cnt1,
                         int E, int RE) {
    int i = blockIdx.x * blockDim.x + threadIdx.x;
    if (i < RE) {
        atomAdd(dego + src[i], 1.f);
        atomicAdd((i < E ? cnt0 : cnt1) + dst[i], 1);
    }
}

__global__ void k_rs(const float* __restrict__ dego, const int* __restrict__ cnt0,
                     const int* __restrict__ cnt1, float* __restrict__ rsdo,
                     float* __restrict__ rsdi, int n) {
    int i = blockIdx.x * blockDim.x + threadIdx.x;
    if (i < n) {
        rsdo[i] = rsqrtf(fmaxf(dego[i], 1.f));
        rsdi[i] = rsqrtf(fmaxf((float)(cnt0[i] + cnt1[i]), 1.f));
    }
}

// ---------- exclusive scan of per-dst counts -> indptr + cursor (one block per relation) ----------
__global__ __launch_bounds__(1024) void k_scan(const int* __restrict__ cnt0, const int* __restrict__ cnt1,
                                               int* __restrict__ ip0, int* __restrict__ ip1,
                                               int* __restrict__ cu0, int* __restrict__ cu1, int n) {
    const int* cnt = blockIdx.x ? cnt1 : cnt0;
    int* ip = blockIdx.x ? ip1 : ip0;
    int* cu = blockIdx.x ? cu1 : cu0;
    __shared__ int part[1024];
    int t = threadIdx.x;
    int seg = (n + 1023) >> 10;
    int lo = t * seg, hi = min(lo + seg, n);
    int s = 0;
    for (int i = lo; i < hi; ++i) s += cnt[i];
    part[t] = s;
    __syncthreads();
    for (int off = 1; off < 1024; off <<= 1) {
        int v = 0;
        if (t >= off) v = part[t - off];
        __syncthreads();
        if (t >= off) part[t] += v;
        __syncthreads();
    }
    int run = (t == 0) ? 0 : part[t - 1];
    for (int i = lo; i < hi; ++i) { ip[i] = run; cu[i] = run; run += cnt[i]; }
    if (t == 1023) ip[n] = run;
}

// ---------- scatter src ids into CSR slots ----------
__global__ void k_scatter(const int* __restrict__ src, const int* __restrict__ dst,
                          int* __restrict__ cursor, int* __restrict__ srcs, int n) {
    int i = blockIdx.x * blockDim.x + threadIdx.x;
    if (i < n) {
        int p = atomicAdd(cursor + dst[i], 1);
        srcs[p] = src[i];
    }
}

// ---------- 128x128 GEMM, tile 64 nodes: Y = X@W + b ----------
__global__ __launch_bounds__(256) void k_gemm(const float* __restrict__ X, const float* __restrict__ W,
                                              const float* __restrict__ bias, float* __restrict__ Y, int n) {
    __shared__ float xs[64 * 128];
    __shared__ float wc[32 * 128];
    int tid = threadIdx.x;
    int nb0 = blockIdx.x * 64;
    for (int i = tid; i < 64 * 32; i += 256) {
        int row = i >> 5, c4 = i & 31;
        float4 v = make_float4(0.f, 0.f, 0.f, 0.f);
        if (nb0 + row < n) v = *(const float4*)(X + (size_t)(nb0 + row) * 128 + c4 * 4);
        *(float4*)(xs + row * 128 + c4 * 4) = v;
    }
    float acc[8][4];
    #pragma unroll
    for (int i = 0; i < 8; ++i)
        #pragma unroll
        for (int c = 0; c < 4; ++c) acc[i][c] = 0.f;
    int col4 = (tid & 31) * 4;
    int r0 = (tid >> 5) * 8;
    for (int kc = 0; kc < 4; ++kc) {
        __syncthreads();
        for (int i = tid; i < 32 * 32; i += 256) {
            int kk = i >> 5, c4 = i & 31;
            *(float4*)(wc + kk * 128 + c4 * 4) = *(const float4*)(W + (size_t)(kc * 32 + kk) * 128 + c4 * 4);
        }
        __syncthreads();
        #pragma unroll
        for (int kk = 0; kk < 32; ++kk) {
            float4 w = *(const float4*)(wc + kk * 128 + col4);
            #pragma unroll
            for (int i = 0; i < 8; ++i) {
                float xv = xs[(r0 + i) * 128 + kc * 32 + kk];
                acc[i][0] += xv * w.x; acc[i][1] += xv * w.y;
                acc[i][2] += xv * w.z; acc[i][3] += xv * w.w;
            }
        }
    }
    float4 b = *(const float4*)(bias + col4);
    #pragma unroll
    for (int i = 0; i < 8; ++i) {
        int row = nb0 + r0 + i;
        if (row < n) {
            float4 o = make_float4(acc[i][0] + b.x, acc[i][1] + b.y, acc[i][2] + b.z, acc[i][3] + b.w);
            *(float4*)(Y + (size_t)row * 128 + col4) = o;
        }
    }
}

// ---------- per-node attention scores from x directly (skinny GEMM N x 128 x 16) ----------
__global__ __launch_bounds__(256) void k_nodescore(const float* __restrict__ x,
                                                   const float* __restrict__ wes, const float* __restrict__ wed,
                                                   const float* __restrict__ ces, const float* __restrict__ ced,
                                                   float* __restrict__ es0, float* __restrict__ es1,
                                                   float* __restrict__ ed0, float* __restrict__ ed1, int n) {
    __shared__ float xs[64 * 132];
    int tid = threadIdx.x;
    int nb0 = blockIdx.x * 64;
    for (int i = tid; i < 64 * 32; i += 256) {
        int row = i >> 5, c4 = i & 31;
        float4 v = make_float4(0.f, 0.f, 0.f, 0.f);
        if (nb0 + row < n) v = *(const float4*)(x + (size_t)(nb0 + row) * 128 + c4 * 4);
        *(float4*)(xs + row * 132 + c4 * 4) = v;
    }
    __syncthreads();
    int node = tid >> 2;
    int gn = nb0 + node;
    if (gn >= n) return;
    #pragma unroll
    for (int q = 0; q < 4; ++q) {
        int j = (tid & 3) + q * 4;          // j = which*8 + r*4 + h
        int which = j >> 3, r = (j >> 2) & 1, h = j & 3;
        const float* w = (which ? wed : wes) + r * 512 + h * 128;
        float acc = (which ? ced : ces)[r * 4 + h];
        #pragma unroll 16
        for (int d = 0; d < 128; ++d) acc += xs[node * 132 + d] * w[d];
        float* outp = which ? (r ? ed1 : ed0) : (r ? es1 : es0);
        outp[(size_t)gn * 4 + h] = acc;
    }
}

// ---------- CSR gather-aggregate: one node per 128 threads, no atomics ----------
// Pass 0 (FINAL=false): f0 = relu(U0/sd0) -> fbuf, hg partial -> hg
// Pass 1 (FINAL=true):  f1, read f0, relation-softmax fuse -> fbuf, hg += partial
template<bool FINAL>
__global__ __launch_bounds__(256) void k_agg(const int* __restrict__ indptr, const int* __restrict__ srcs,
                                             const float* __restrict__ x, const float* __restrict__ rsdo,
                                             const float* __restrict__ fs, const float* __restrict__ es,
                                             const float* __restrict__ ed, const float* __restrict__ relfeat,
                                             float* __restrict__ fbuf, float* __restrict__ hg, int n) {
    int node = blockIdx.x * 2 + (threadIdx.x >> 7);
    if (node >= n) return;
    int j = threadIdx.x & 127;
    int h = j >> 5;
    float edv = ed[(size_t)node * 4 + h];
    int b0 = indptr[node], e0 = indptr[node + 1];
    float accU = 0.f, accH = 0.f, sd = 0.f;
    for (int e = b0; e < e0; ++e) {
        int s = srcs[e];
        float exv = __expf(leaky(es[(size_t)s * 4 + h] + edv));
        accU += exv * fs[(size_t)s * 128 + j];
        accH += rsdo[s] * x[(size_t)s * 128 + j];
        sd += exv;
    }
    float f = fmaxf(accU / (sd + 1e-9f), 0.f);
    size_t rowoff = (size_t)node * 128 + j;
    if (!FINAL) {
        fbuf[rowoff] = f;
        hg[rowoff] = accH;
    } else {
        float f0 = fbuf[rowoff];
        float sc0 = f0 * relfeat[j];
        float sc1 = f * relfeat[128 + j];
        #pragma unroll
        for (int m = 1; m < 32; m <<= 1) {
            sc0 += __shfl_xor(sc0, m, 64);
            sc1 += __shfl_xor(sc1, m, 64);
        }
        sc0 = leaky(sc0); sc1 = leaky(sc1);
        float mx = fmaxf(sc0, sc1);
        float p0 = __expf(sc0 - mx), p1 = __expf(sc1 - mx);
        float inv = 1.f / (p0 + p1);
        fbuf[rowoff] = (p0 * f0 + p1 * f) * inv;
        hg[rowoff] += accH;
    }
}

// ---------- final: node_level GEMM (hg * rsdi @ W_g) + feat_dst GEMM (x @ W_node) + epilogue ----------
__global__ __launch_bounds__(256) void k_final(const float* __restrict__ x,
                                               const float* __restrict__ Wn, const float* __restrict__ bn,
                                               const float* __restrict__ Wg, const float* __restrict__ bg,
                                               const float* __restrict__ rsdi,
                                               const float* __restrict__ fused,
                                               const float* __restrict__ residual_w, const float* __restrict__ scale_w,
                                               float* __restrict__ out, int n) {
    __shared__ float xs[64 * 128];
    __shared__ float wc[32 * 128];
    int tid = threadIdx.x;
    int nb0 = blockIdx.x * 64;
    int col4 = (tid & 31) * 4;
    int r0 = (tid >> 5) * 8;
    float accg[8][4], accn[8][4];

    // ---- phase A: node_level pre-activation = (hg * rsdi) @ Wg ----
    for (int i = tid; i < 64 * 32; i += 256) {
        int row = i >> 5, c4 = i & 31;
        float4 v = make_float4(0.f, 0.f, 0.f, 0.f);
        if (nb0 + row < n) {
            float sc = rsdi[nb0 + row];
            v = *(const float4*)(out + (size_t)(nb0 + row) * 128 + c4 * 4);
            v.x *= sc; v.y *= sc; v.z *= sc; v.w *= sc;
        }
        *(float4*)(xs + row * 128 + c4 * 4) = v;
    }
    #pragma unroll
    for (int i = 0; i < 8; ++i)
        #pragma unroll
        for (int c = 0; c < 4; ++c) accg[i][c] = 0.f;
    for (int kc = 0; kc < 4; ++kc) {
        __syncthreads();
        for (int i = tid; i < 32 * 32; i += 256) {
            int kk = i >> 5, c4 = i & 31;
            *(float4*)(wc + kk * 128 + c4 * 4) = *(const float4*)(Wg + (size_t)(kc * 32 + kk) * 128 + c4 * 4);
        }
        __syncthreads();
        #pragma unroll
        for (int kk = 0; kk < 32; ++kk) {
            float4 w = *(const float4*)(wc + kk * 128 + col4);
            #pragma unroll
            for (int i = 0; i < 8; ++i) {
                float xv = xs[(r0 + i) * 128 + kc * 32 + kk];
                accg[i][0] += xv * w.x; accg[i][1] += xv * w.y;
                accg[i][2] += xv * w.z; accg[i][3] += xv * w.w;
            }
        }
    }
    __syncthreads();

    // ---- phase B: feat_dst pre-bias = x @ Wn ----
    for (int i = tid; i < 64 * 32; i += 256) {
        int row = i >> 5, c4 = i & 31;
        float4 v = make_float4(0.f, 0.f, 0.f, 0.f);
        if (nb0 + row < n) v = *(const float4*)(x + (size_t)(nb0 + row) * 128 + c4 * 4);
        *(float4*)(xs + row * 128 + c4 * 4) = v;
    }
    #pragma unroll
    for (int i = 0; i < 8; ++i)
        #pragma unroll
        for (int c = 0; c < 4; ++c) accn[i][c] = 0.f;
    for (int kc = 0; kc < 4; ++kc) {
        __syncthreads();
        for (int i = tid; i < 32 * 32; i += 256) {
            int kk = i >> 5, c4 = i & 31;
            *(float4*)(wc + kk * 128 + c4 * 4) = *(const float4*)(Wn + (size_t)(kc * 32 + kk) * 128 + c4 * 4);
        }
        __syncthreads();
        #pragma unroll
        for (int kk = 0; kk < 32; ++kk) {
            float4 w = *(const float4*)(wc + kk * 128 + col4);
            #pragma unroll
            for (int i = 0; i < 8; ++i) {
                float xv = xs[(r0 + i) * 128 + kc * 32 + kk];
                accn[i][0] += xv * w.x; accn[i][1] += xv * w.y;
                accn[i][2] += xv * w.z; accn[i][3] += xv * w.w;
            }
        }
    }

    // ---- epilogue ----
    float beta = 1.f / (1.f + __expf(-residual_w[0]));
    float av = 1.f / (1.f + __expf(-scale_w[0]));
    float4 bgv = *(const float4*)(bg + col4);
    float4 bnv = *(const float4*)(bn + col4);
    #pragma unroll
    for (int i = 0; i < 8; ++i) {
        int row = nb0 + r0 + i;
        if (row < n) {
            float4 fu4 = *(const float4*)(fused + (size_t)row * 128 + col4);
            float4 o;
            float fd, fu, nl;
            fd = accn[i][0] + bnv.x;
            fu = beta * fu4.x + (1.f - beta) * fd;
            nl = fmaxf(accg[i][0] + bgv.x, 0.f);
            o.x = av * fu + (1.f - av) * nl;
            fd = accn[i][1] + bnv.y;
            fu = beta * fu4.y + (1.f - beta) * fd;
            nl = fmaxf(accg[i][1] + bgv.y, 0.f);
            o.y = av * fu + (1.f - av) * nl;
            fd = accn[i][2] + bnv.z;
            fu = beta * fu4.z + (1.f - beta) * fd;
            nl = fmaxf(accg[i][2] + bgv.z, 0.f);
            o.z = av * fu + (1.f - av) * nl;
            fd = accn[i][3] + bnv.w;
            fu = beta * fu4.w + (1.f - beta) * fd;
            nl = fmaxf(accg[i][3] + bgv.w, 0.f);
            o.w = av * fu + (1.f - av) * nl;
            *(float4*)(out + (size_t)row * 128 + col4) = o;
        }
    }
}

extern "C" void kernel_launch(void* const* d_in, const int* in_sizes, int n_in,
                              void* d_out, int out_size, void* d_ws, size_t ws_size,
                              hipStream_t stream) {
    const float* x         = (const float*)d_in[0];
    const int*   src       = (const int*)d_in[1];
    const int*   dst       = (const int*)d_in[2];
    const float* rel_emb   = (const float*)d_in[3];
    const float* W_node    = (const float*)d_in[4];
    const float* b_node    = (const float*)d_in[5];
    const float* W_src     = (const float*)d_in[6];
    const float* b_src     = (const float*)d_in[7];
    const float* W_relT    = (const float*)d_in[8];
    const float* W_relprop = (const float*)d_in[9];
    const float* b_relprop = (const float*)d_in[10];
    const float* W_fuse    = (const float*)d_in[11];
    const float* resid_w   = (const float*)d_in[12];
    const float* scale_w   = (const float*)d_in[13];
    const float* W_g       = (const float*)d_in[14];
    const float* b_g       = (const float*)d_in[15];
    float* out = (float*)d_out;

    const int N = in_sizes[0] / 128;
    const int RE = in_sizes[1];
    const int E = RE / 2;

    // workspace: ~121 MB at N=1e5, E=1e6
    float* ws = (float*)d_ws;
    size_t o = 0;
    float* fs   = ws + o; o += (size_t)N * 128;  // per-relation feat_src (reused)
    float* fbuf = ws + o; o += (size_t)N * 128;  // f0 then fused
    float* es0  = ws + o; o += (size_t)N * 4;
    float* es1  = ws + o; o += (size_t)N * 4;
    float* ed0  = ws + o; o += (size_t)N * 4;
    float* ed1  = ws + o; o += (size_t)N * 4;
    float* rsdo = ws + o; o += N;
    float* rsdi = ws + o; o += N;
    float* relfeat = ws + o; o += 256;
    float* wes  = ws + o; o += 1024;
    float* wed  = ws + o; o += 1024;
    float* ces  = ws + o; o += 16;
    float* ced  = ws + o; o += 16;
    float* dego = ws + o; o += N;                // zero region start (dego, cnt0, cnt1)
    int* ibase = (int*)(ws + o);
    int* cnt0 = ibase;            // N
    int* cnt1 = ibase + N;        // N  (zero region end)
    int* ip0  = ibase + 2 * (size_t)N;
    int* ip1  = ip0 + N + 1;
    int* cu0  = ip1 + N + 1;
    int* cu1  = cu0 + N + 1;
    int* srcs0 = cu1 + N + 1;     // E
    int* srcs1 = srcs0 + E;       // E

    hipMemsetAsync(dego, 0, sizeof(float) * (size_t)3 * N, stream);

    k_small<<<1, 512, 0, stream>>>(rel_emb, W_relT, W_relprop, b_relprop, W_fuse,
                                   W_src, b_src, W_node, b_node,
                                   relfeat, wes, wed, ces, ced);
    k_degree<<<(RE + 255) / 256, 256, 0, stream>>>(src, dst, dego, cnt0, cnt1, E, RE);
    k_rs<<<(N + 255) / 256, 256, 0, stream>>>(dego, cnt0, cnt1, rsdo, rsdi, N);
    k_scan<<<2, 1024, 0, stream>>>(cnt0, cnt1, ip0, ip1, cu0, cu1, N);
    k_scatter<<<(E + 255) / 256, 256, 0, stream>>>(src, dst, cu0, srcs0, E);
    k_scatter<<<(E + 255) / 256, 256, 0, stream>>>(src + E, dst + E, cu1, srcs1, E);

    dim3 ggrid((N + 63) / 64);
    k_nodescore<<<ggrid, 256, 0, stream>>>(x, wes, wed, ces, ced, es0, es1, ed0, ed1, N);

    // relation 0: feat_src GEMM + gather-aggregate
    k_gemm<<<ggrid, 256, 0, stream>>>(x, W_src, b_src, fs, N);
    k_agg<false><<<(N + 1) / 2, 256, 0, stream>>>(ip0, srcs0, x, rsdo, fs, es0, ed0,
                                                  relfeat, fbuf, out, N);
    // relation 1: feat_src GEMM + gather-aggregate + fusion epilogue
    k_gemm<<<ggrid, 256, 0, stream>>>(x, W_src + 16384, b_src + 128, fs, N);
    k_agg<true><<<(N + 1) / 2, 256, 0, stream>>>(ip1, srcs1, x, rsdo, fs, es1, ed1,
                                                 relfeat, fbuf, out, N);

    k_final<<<ggrid, 256, 0, stream>>>(x, W_node, b_node, W_g, b_g, rsdi,
                                       fbuf, resid_w, scale_w, out, N);
}

// Round 4
// 994.152 us; speedup vs baseline: 2.5453x; 1.4184x over previous
//
#include <hip/hip_runtime.h>
#include <cstddef>

#define NEG_SLOPE 0.2f

__device__ __forceinline__ float leaky(float v) { return v >= 0.f ? v : NEG_SLOPE * v; }
__device__ __forceinline__ void atomAdd(float* p, float v) { unsafeAtomicAdd(p, v); }

// pack two f32 into two bf16 (RNE) in one uint: lo = a, hi = b
__device__ __forceinline__ unsigned int bfpack(float a, float b) {
    unsigned int ua = __float_as_uint(a);
    ua += 0x7fffu + ((ua >> 16) & 1u);
    unsigned int ub = __float_as_uint(b);
    ub += 0x7fffu + ((ub >> 16) & 1u);
    return (ua >> 16) | (ub & 0xffff0000u);
}
__device__ __forceinline__ float bflo(unsigned int u) { return __uint_as_float(u << 16); }
__device__ __forceinline__ float bfhi(unsigned int u) { return __uint_as_float(u & 0xffff0000u); }

// ---------- tiny per-relation constants + attention-vector projections ----------
__global__ void k_small(const float* __restrict__ rel_emb, const float* __restrict__ W_relT,
                        const float* __restrict__ W_relprop, const float* __restrict__ b_relprop,
                        const float* __restrict__ W_fuse, const float* __restrict__ W_src,
                        const float* __restrict__ b_src, const float* __restrict__ W_node,
                        const float* __restrict__ b_node,
                        float* __restrict__ relfeat, float* __restrict__ wes, float* __restrict__ wed,
                        float* __restrict__ ces, float* __restrict__ ced) {
    __shared__ float av[512];     // attn vectors [r][h][i][d]
    __shared__ float rp[2][128];  // rel_prop
    int t = threadIdx.x;  // 512 threads
    {
        int r = t >> 8, m = t & 255;
        float acc = 0.f;
        const float* re = rel_emb + r * 64;
        const float* w = W_relT + (size_t)r * 16384 + m;
        #pragma unroll 8
        for (int k = 0; k < 64; ++k) acc += re[k] * w[(size_t)k * 256];
        av[t] = acc;
    }
    if (t < 256) {
        int r = t >> 7, m = t & 127;
        float acc = b_relprop[t];
        const float* re = rel_emb + r * 64;
        const float* w = W_relprop + (size_t)r * 8192 + m;
        #pragma unroll 8
        for (int k = 0; k < 64; ++k) acc += re[k] * w[(size_t)k * 128];
        rp[r][m] = acc;
    }
    __syncthreads();
    if (t < 256) {  // relation fusing feature
        int r = t >> 7, h = (t >> 5) & 3, d = t & 31;
        float acc = 0.f;
        const float* w = W_fuse + ((size_t)(r * 4 + h) * 32) * 32 + d;
        #pragma unroll
        for (int k = 0; k < 32; ++k) acc += rp[r][h * 32 + k] * w[(size_t)k * 32];
        relfeat[t] = acc;
    }
    // project attn vectors through weights so edge scores come straight from x
    for (int idx = t; idx < 2048; idx += 512) {
        int which = idx >> 10, rem = idx & 1023;
        int r = rem >> 9, h = (rem >> 7) & 3, c = rem & 127;
        const float* W = which ? W_node : (W_src + (size_t)r * 16384);
        const float* a = av + r * 256 + h * 64 + which * 32;
        float acc = 0.f;
        #pragma unroll
        for (int d = 0; d < 32; ++d) acc += W[(size_t)c * 128 + h * 32 + d] * a[d];
        (which ? wed : wes)[rem] = acc;
    }
    if (t < 16) {
        int which = t >> 3, r = (t >> 2) & 1, h = t & 3;
        const float* b = which ? b_node : (b_src + r * 128);
        const float* a = av + r * 256 + h * 64 + which * 32;
        float acc = 0.f;
        #pragma unroll
        for (int d = 0; d < 32; ++d) acc += b[h * 32 + d] * a[d];
        (which ? ced : ces)[r * 4 + h] = acc;
    }
}

// ---------- degrees + per-edge rank (CSR slot) ----------
__global__ void k_degree(const int* __restrict__ src, const int* __restrict__ dst,
                         float* __restrict__ dego, int* __restrict__ cnt0, int* __restrict__ cnt1,
                         int* __restrict__ rank, int E, int RE) {
    int i = blockIdx.x * blockDim.x + threadIdx.x;
    if (i < RE) {
        atomAdd(dego + src[i], 1.f);
        rank[i] = atomicAdd((i < E ? cnt0 : cnt1) + dst[i], 1);
    }
}

__global__ void k_rs(const float* __restrict__ dego, const int* __restrict__ cnt0,
                     const int* __restrict__ cnt1, float* __restrict__ rsdo,
                     float* __restrict__ rsdi, int n) {
    int i = blockIdx.x * blockDim.x + threadIdx.x;
    if (i < n) {
        rsdo[i] = rsqrtf(fmaxf(dego[i], 1.f));
        rsdi[i] = rsqrtf(fmaxf((float)(cnt0[i] + cnt1[i]), 1.f));
    }
}

// ---------- exclusive scan of per-dst counts -> indptr (one block per relation) ----------
__global__ __launch_bounds__(1024) void k_scan(const int* __restrict__ cnt0, const int* __restrict__ cnt1,
                                               int* __restrict__ ip0, int* __restrict__ ip1, int n) {
    const int* cnt = blockIdx.x ? cnt1 : cnt0;
    int* ip = blockIdx.x ? ip1 : ip0;
    __shared__ int part[1024];
    int t = threadIdx.x;
    int seg = (n + 1023) >> 10;
    int lo = t * seg, hi = min(lo + seg, n);
    int s = 0;
    for (int i = lo; i < hi; ++i) s += cnt[i];
    part[t] = s;
    __syncthreads();
    for (int off = 1; off < 1024; off <<= 1) {
        int v = 0;
        if (t >= off) v = part[t - off];
        __syncthreads();
        if (t >= off) part[t] += v;
        __syncthreads();
    }
    int run = (t == 0) ? 0 : part[t - 1];
    for (int i = lo; i < hi; ++i) { ip[i] = run; run += cnt[i]; }
    if (t == 1023) ip[n] = run;
}

// ---------- scatter src ids into CSR slots (no atomics; rank precomputed) ----------
__global__ void k_scatter(const int* __restrict__ src, const int* __restrict__ dst,
                          const int* __restrict__ rank,
                          const int* __restrict__ ip0, const int* __restrict__ ip1,
                          int* __restrict__ srcs0, int* __restrict__ srcs1, int E, int RE) {
    int i = blockIdx.x * blockDim.x + threadIdx.x;
    if (i < RE) {
        int r = (i >= E);
        int p = (r ? ip1 : ip0)[dst[i]] + rank[i];
        (r ? srcs1 : srcs0)[p] = src[i];
    }
}

// ---------- both relations' feat_src GEMMs -> packed bf16 (x read once) ----------
__global__ __launch_bounds__(256) void k_gemm2(const float* __restrict__ X, const float* __restrict__ W_src,
                                               const float* __restrict__ b_src,
                                               unsigned int* __restrict__ fs0p, unsigned int* __restrict__ fs1p,
                                               int n) {
    __shared__ float xs[64 * 128];
    __shared__ float wc[32 * 128];
    int tid = threadIdx.x;
    int nb0 = blockIdx.x * 64;
    for (int i = tid; i < 64 * 32; i += 256) {
        int row = i >> 5, c4 = i & 31;
        float4 v = make_float4(0.f, 0.f, 0.f, 0.f);
        if (nb0 + row < n) v = *(const float4*)(X + (size_t)(nb0 + row) * 128 + c4 * 4);
        *(float4*)(xs + row * 128 + c4 * 4) = v;
    }
    int col4 = (tid & 31) * 4;
    int r0 = (tid >> 5) * 8;
    for (int rel = 0; rel < 2; ++rel) {
        const float* W = W_src + (size_t)rel * 16384;
        float acc[8][4];
        #pragma unroll
        for (int i = 0; i < 8; ++i)
            #pragma unroll
            for (int c = 0; c < 4; ++c) acc[i][c] = 0.f;
        for (int kc = 0; kc < 4; ++kc) {
            __syncthreads();
            for (int i = tid; i < 32 * 32; i += 256) {
                int kk = i >> 5, c4 = i & 31;
                *(float4*)(wc + kk * 128 + c4 * 4) = *(const float4*)(W + (size_t)(kc * 32 + kk) * 128 + c4 * 4);
            }
            __syncthreads();
            #pragma unroll
            for (int kk = 0; kk < 32; ++kk) {
                float4 w = *(const float4*)(wc + kk * 128 + col4);
                #pragma unroll
                for (int i = 0; i < 8; ++i) {
                    float xv = xs[(r0 + i) * 128 + kc * 32 + kk];
                    acc[i][0] += xv * w.x; acc[i][1] += xv * w.y;
                    acc[i][2] += xv * w.z; acc[i][3] += xv * w.w;
                }
            }
        }
        float4 b = *(const float4*)(b_src + rel * 128 + col4);
        unsigned int* fsp = rel ? fs1p : fs0p;
        #pragma unroll
        for (int i = 0; i < 8; ++i) {
            int row = nb0 + r0 + i;
            if (row < n) {
                uint2 w;
                w.x = bfpack(acc[i][0] + b.x, acc[i][1] + b.y);
                w.y = bfpack(acc[i][2] + b.z, acc[i][3] + b.w);
                *(uint2*)(fsp + (size_t)row * 64 + (col4 >> 1)) = w;
            }
        }
        __syncthreads();
    }
}

// ---------- per-node attention scores + xn = bf16(x * rsdo) ----------
__global__ __launch_bounds__(256) void k_nodescore(const float* __restrict__ x,
                                                   const float* __restrict__ rsdo,
                                                   const float* __restrict__ wes, const float* __restrict__ wed,
                                                   const float* __restrict__ ces, const float* __restrict__ ced,
                                                   float* __restrict__ es0, float* __restrict__ es1,
                                                   float* __restrict__ ed0, float* __restrict__ ed1,
                                                   unsigned int* __restrict__ xnp, int n) {
    __shared__ float xs[64 * 132];
    int tid = threadIdx.x;
    int nb0 = blockIdx.x * 64;
    for (int i = tid; i < 64 * 32; i += 256) {
        int row = i >> 5, c4 = i & 31;
        float4 v = make_float4(0.f, 0.f, 0.f, 0.f);
        if (nb0 + row < n) v = *(const float4*)(x + (size_t)(nb0 + row) * 128 + c4 * 4);
        *(float4*)(xs + row * 132 + c4 * 4) = v;
    }
    __syncthreads();
    // xn write (packed bf16 of x*rsdo)
    for (int i = tid; i < 64 * 64; i += 256) {
        int row = i >> 6, c2 = i & 63;
        int gr = nb0 + row;
        if (gr < n) {
            float sc = rsdo[gr];
            xnp[(size_t)gr * 64 + c2] = bfpack(xs[row * 132 + 2 * c2] * sc, xs[row * 132 + 2 * c2 + 1] * sc);
        }
    }
    int node = tid >> 2;
    int gn = nb0 + node;
    if (gn >= n) return;
    #pragma unroll
    for (int q = 0; q < 4; ++q) {
        int j = (tid & 3) + q * 4;          // j = which*8 + r*4 + h
        int which = j >> 3, r = (j >> 2) & 1, h = j & 3;
        const float* w = (which ? wed : wes) + r * 512 + h * 128;
        float acc = (which ? ced : ces)[r * 4 + h];
        #pragma unroll 16
        for (int d = 0; d < 128; ++d) acc += xs[node * 132 + d] * w[d];
        float* outp = which ? (r ? ed1 : ed0) : (r ? es1 : es0);
        outp[(size_t)gn * 4 + h] = acc;
    }
}

// ---------- merged CSR gather-aggregate: one wave per node, both relations, fused epilogue ----------
__global__ __launch_bounds__(256) void k_agg(const int* __restrict__ ip0, const int* __restrict__ srcs0,
                                             const int* __restrict__ ip1, const int* __restrict__ srcs1,
                                             const unsigned int* __restrict__ xnp,
                                             const unsigned int* __restrict__ fs0p, const unsigned int* __restrict__ fs1p,
                                             const float* __restrict__ es0, const float* __restrict__ es1,
                                             const float* __restrict__ ed0, const float* __restrict__ ed1,
                                             const float* __restrict__ relfeat,
                                             float* __restrict__ fbuf, float* __restrict__ hg, int n) {
    int node = blockIdx.x * 4 + (threadIdx.x >> 6);   // one 64-lane wave per node
    if (node >= n) return;
    int j2 = threadIdx.x & 63;                        // channel pair (2*j2, 2*j2+1)
    int h = j2 >> 4;
    float ed0v = ed0[(size_t)node * 4 + h];
    float ed1v = ed1[(size_t)node * 4 + h];
    float aU0x = 0.f, aU0y = 0.f, aU1x = 0.f, aU1y = 0.f, aHx = 0.f, aHy = 0.f;
    float s0 = 0.f, s1 = 0.f;
    int b0 = ip0[node], e0 = ip0[node + 1];
    #pragma unroll 2
    for (int k = b0; k < e0; ++k) {
        int s = srcs0[k];
        float ex = __expf(leaky(es0[(size_t)s * 4 + h] + ed0v));
        unsigned int fv = fs0p[(size_t)s * 64 + j2];
        unsigned int xv = xnp[(size_t)s * 64 + j2];
        aU0x += ex * bflo(fv); aU0y += ex * bfhi(fv);
        aHx += bflo(xv); aHy += bfhi(xv);
        s0 += ex;
    }
    int b1 = ip1[node], e1 = ip1[node + 1];
    #pragma unroll 2
    for (int k = b1; k < e1; ++k) {
        int s = srcs1[k];
        float ex = __expf(leaky(es1[(size_t)s * 4 + h] + ed1v));
        unsigned int fv = fs1p[(size_t)s * 64 + j2];
        unsigned int xv = xnp[(size_t)s * 64 + j2];
        aU1x += ex * bflo(fv); aU1y += ex * bfhi(fv);
        aHx += bflo(xv); aHy += bfhi(xv);
        s1 += ex;
    }
    float i0 = 1.f / (s0 + 1e-9f), i1 = 1.f / (s1 + 1e-9f);
    float f0x = fmaxf(aU0x * i0, 0.f), f0y = fmaxf(aU0y * i0, 0.f);
    float f1x = fmaxf(aU1x * i1, 0.f), f1y = fmaxf(aU1y * i1, 0.f);
    // relation-fusion softmax (reduce over 16 lanes of this head)
    float sc0 = f0x * relfeat[2 * j2] + f0y * relfeat[2 * j2 + 1];
    float sc1 = f1x * relfeat[128 + 2 * j2] + f1y * relfeat[128 + 2 * j2 + 1];
    #pragma unroll
    for (int m = 1; m < 16; m <<= 1) {
        sc0 += __shfl_xor(sc0, m, 64);
        sc1 += __shfl_xor(sc1, m, 64);
    }
    sc0 = leaky(sc0); sc1 = leaky(sc1);
    float mx = fmaxf(sc0, sc1);
    float p0 = __expf(sc0 - mx), p1 = __expf(sc1 - mx);
    float inv = 1.f / (p0 + p1);
    p0 *= inv; p1 *= inv;
    float2 fu = make_float2(p0 * f0x + p1 * f1x, p0 * f0y + p1 * f1y);
    *(float2*)(fbuf + (size_t)node * 128 + 2 * j2) = fu;
    *(float2*)(hg + (size_t)node * 128 + 2 * j2) = make_float2(aHx, aHy);
}

// ---------- final: node_level GEMM (hg * rsdi @ W_g) + feat_dst GEMM (x @ W_node) + epilogue ----------
__global__ __launch_bounds__(256) void k_final(const float* __restrict__ x,
                                               const float* __restrict__ Wn, const float* __restrict__ bn,
                                               const float* __restrict__ Wg, const float* __restrict__ bg,
                                               const float* __restrict__ rsdi,
                                               const float* __restrict__ fused,
                                               const float* __restrict__ residual_w, const float* __restrict__ scale_w,
                                               float* __restrict__ out, int n) {
    __shared__ float xs[64 * 128];
    __shared__ float wc[32 * 128];
    int tid = threadIdx.x;
    int nb0 = blockIdx.x * 64;
    int col4 = (tid & 31) * 4;
    int r0 = (tid >> 5) * 8;
    float accg[8][4], accn[8][4];

    // ---- phase A: node_level pre-activation = (hg * rsdi) @ Wg ----
    for (int i = tid; i < 64 * 32; i += 256) {
        int row = i >> 5, c4 = i & 31;
        float4 v = make_float4(0.f, 0.f, 0.f, 0.f);
        if (nb0 + row < n) {
            float sc = rsdi[nb0 + row];
            v = *(const float4*)(out + (size_t)(nb0 + row) * 128 + c4 * 4);
            v.x *= sc; v.y *= sc; v.z *= sc; v.w *= sc;
        }
        *(float4*)(xs + row * 128 + c4 * 4) = v;
    }
    #pragma unroll
    for (int i = 0; i < 8; ++i)
        #pragma unroll
        for (int c = 0; c < 4; ++c) accg[i][c] = 0.f;
    for (int kc = 0; kc < 4; ++kc) {
        __syncthreads();
        for (int i = tid; i < 32 * 32; i += 256) {
            int kk = i >> 5, c4 = i & 31;
            *(float4*)(wc + kk * 128 + c4 * 4) = *(const float4*)(Wg + (size_t)(kc * 32 + kk) * 128 + c4 * 4);
        }
        __syncthreads();
        #pragma unroll
        for (int kk = 0; kk < 32; ++kk) {
            float4 w = *(const float4*)(wc + kk * 128 + col4);
            #pragma unroll
            for (int i = 0; i < 8; ++i) {
                float xv = xs[(r0 + i) * 128 + kc * 32 + kk];
                accg[i][0] += xv * w.x; accg[i][1] += xv * w.y;
                accg[i][2] += xv * w.z; accg[i][3] += xv * w.w;
            }
        }
    }
    __syncthreads();

    // ---- phase B: feat_dst pre-bias = x @ Wn ----
    for (int i = tid; i < 64 * 32; i += 256) {
        int row = i >> 5, c4 = i & 31;
        float4 v = make_float4(0.f, 0.f, 0.f, 0.f);
        if (nb0 + row < n) v = *(const float4*)(x + (size_t)(nb0 + row) * 128 + c4 * 4);
        *(float4*)(xs + row * 128 + c4 * 4) = v;
    }
    #pragma unroll
    for (int i = 0; i < 8; ++i)
        #pragma unroll
        for (int c = 0; c < 4; ++c) accn[i][c] = 0.f;
    for (int kc = 0; kc < 4; ++kc) {
        __syncthreads();
        for (int i = tid; i < 32 * 32; i += 256) {
            int kk = i >> 5, c4 = i & 31;
            *(float4*)(wc + kk * 128 + c4 * 4) = *(const float4*)(Wn + (size_t)(kc * 32 + kk) * 128 + c4 * 4);
        }
        __syncthreads();
        #pragma unroll
        for (int kk = 0; kk < 32; ++kk) {
            float4 w = *(const float4*)(wc + kk * 128 + col4);
            #pragma unroll
            for (int i = 0; i < 8; ++i) {
                float xv = xs[(r0 + i) * 128 + kc * 32 + kk];
                accn[i][0] += xv * w.x; accn[i][1] += xv * w.y;
                accn[i][2] += xv * w.z; accn[i][3] += xv * w.w;
            }
        }
    }

    // ---- epilogue ----
    float beta = 1.f / (1.f + __expf(-residual_w[0]));
    float av = 1.f / (1.f + __expf(-scale_w[0]));
    float4 bgv = *(const float4*)(bg + col4);
    float4 bnv = *(const float4*)(bn + col4);
    #pragma unroll
    for (int i = 0; i < 8; ++i) {
        int row = nb0 + r0 + i;
        if (row < n) {
            float4 fu4 = *(const float4*)(fused + (size_t)row * 128 + col4);
            float4 o;
            float fd, fu, nl;
            fd = accn[i][0] + bnv.x;
            fu = beta * fu4.x + (1.f - beta) * fd;
            nl = fmaxf(accg[i][0] + bgv.x, 0.f);
            o.x = av * fu + (1.f - av) * nl;
            fd = accn[i][1] + bnv.y;
            fu = beta * fu4.y + (1.f - beta) * fd;
            nl = fmaxf(accg[i][1] + bgv.y, 0.f);
            o.y = av * fu + (1.f - av) * nl;
            fd = accn[i][2] + bnv.z;
            fu = beta * fu4.z + (1.f - beta) * fd;
            nl = fmaxf(accg[i][2] + bgv.z, 0.f);
            o.z = av * fu + (1.f - av) * nl;
            fd = accn[i][3] + bnv.w;
            fu = beta * fu4.w + (1.f - beta) * fd;
            nl = fmaxf(accg[i][3] + bgv.w, 0.f);
            o.w = av * fu + (1.f - av) * nl;
            *(float4*)(out + (size_t)row * 128 + col4) = o;
        }
    }
}

extern "C" void kernel_launch(void* const* d_in, const int* in_sizes, int n_in,
                              void* d_out, int out_size, void* d_ws, size_t ws_size,
                              hipStream_t stream) {
    const float* x         = (const float*)d_in[0];
    const int*   src       = (const int*)d_in[1];
    const int*   dst       = (const int*)d_in[2];
    const float* rel_emb   = (const float*)d_in[3];
    const float* W_node    = (const float*)d_in[4];
    const float* b_node    = (const float*)d_in[5];
    const float* W_src     = (const float*)d_in[6];
    const float* b_src     = (const float*)d_in[7];
    const float* W_relT    = (const float*)d_in[8];
    const float* W_relprop = (const float*)d_in[9];
    const float* b_relprop = (const float*)d_in[10];
    const float* W_fuse    = (const float*)d_in[11];
    const float* resid_w   = (const float*)d_in[12];
    const float* scale_w   = (const float*)d_in[13];
    const float* W_g       = (const float*)d_in[14];
    const float* b_g       = (const float*)d_in[15];
    float* out = (float*)d_out;

    const int N = in_sizes[0] / 128;
    const int RE = in_sizes[1];
    const int E = RE / 2;

    // workspace: ~153 MB at N=1e5, E=1e6
    float* ws = (float*)d_ws;
    size_t o = 0;
    float* fbuf = ws + o; o += (size_t)N * 128;                 // fused attention features (f32)
    unsigned int* fs0p = (unsigned int*)(ws + o); o += (size_t)N * 64;  // bf16x2 feat_src r0
    unsigned int* fs1p = (unsigned int*)(ws + o); o += (size_t)N * 64;  // bf16x2 feat_src r1
    unsigned int* xnp  = (unsigned int*)(ws + o); o += (size_t)N * 64;  // bf16x2 x*rsdo
    float* es0  = ws + o; o += (size_t)N * 4;
    float* es1  = ws + o; o += (size_t)N * 4;
    float* ed0  = ws + o; o += (size_t)N * 4;
    float* ed1  = ws + o; o += (size_t)N * 4;
    float* rsdo = ws + o; o += N;
    float* rsdi = ws + o; o += N;
    float* relfeat = ws + o; o += 256;
    float* wes  = ws + o; o += 1024;
    float* wed  = ws + o; o += 1024;
    float* ces  = ws + o; o += 16;
    float* ced  = ws + o; o += 16;
    float* dego = ws + o; o += N;           // memset region start
    int* cnt0 = (int*)(ws + o); o += N;
    int* cnt1 = (int*)(ws + o); o += N;     // memset region end (3N * 4B)
    int* ip0  = (int*)(ws + o); o += N + 1;
    int* ip1  = (int*)(ws + o); o += N + 1;
    int* rank = (int*)(ws + o); o += RE;
    int* srcs0 = (int*)(ws + o); o += E;
    int* srcs1 = (int*)(ws + o); o += E;

    hipMemsetAsync(dego, 0, sizeof(float) * (size_t)3 * N, stream);

    k_small<<<1, 512, 0, stream>>>(rel_emb, W_relT, W_relprop, b_relprop, W_fuse,
                                   W_src, b_src, W_node, b_node,
                                   relfeat, wes, wed, ces, ced);
    k_degree<<<(RE + 255) / 256, 256, 0, stream>>>(src, dst, dego, cnt0, cnt1, rank, E, RE);
    k_rs<<<(N + 255) / 256, 256, 0, stream>>>(dego, cnt0, cnt1, rsdo, rsdi, N);
    k_scan<<<2, 1024, 0, stream>>>(cnt0, cnt1, ip0, ip1, N);
    k_scatter<<<(RE + 255) / 256, 256, 0, stream>>>(src, dst, rank, ip0, ip1, srcs0, srcs1, E, RE);

    dim3 ggrid((N + 63) / 64);
    k_gemm2<<<ggrid, 256, 0, stream>>>(x, W_src, b_src, fs0p, fs1p, N);
    k_nodescore<<<ggrid, 256, 0, stream>>>(x, rsdo, wes, wed, ces, ced, es0, es1, ed0, ed1, xnp, N);

    k_agg<<<(N + 3) / 4, 256, 0, stream>>>(ip0, srcs0, ip1, srcs1, xnp, fs0p, fs1p,
                                           es0, es1, ed0, ed1, relfeat, fbuf, out, N);

    k_final<<<ggrid, 256, 0, stream>>>(x, W_node, b_node, W_g, b_g, rsdi,
                                       fbuf, resid_w, scale_w, out, N);
}

// Round 5
// 691.674 us; speedup vs baseline: 3.6585x; 1.4373x over previous
//
#include <hip/hip_runtime.h>
#include <cstddef>

#define NEG_SLOPE 0.2f

__device__ __forceinline__ float leaky(float v) { return v >= 0.f ? v : NEG_SLOPE * v; }

// pack two f32 into two bf16 (RNE) in one uint: lo = a, hi = b
__device__ __forceinline__ unsigned int bfpack(float a, float b) {
    unsigned int ua = __float_as_uint(a);
    ua += 0x7fffu + ((ua >> 16) & 1u);
    unsigned int ub = __float_as_uint(b);
    ub += 0x7fffu + ((ub >> 16) & 1u);
    return (ua >> 16) | (ub & 0xffff0000u);
}
__device__ __forceinline__ float bflo(unsigned int u) { return __uint_as_float(u << 16); }
__device__ __forceinline__ float bfhi(unsigned int u) { return __uint_as_float(u & 0xffff0000u); }

// ---------- tiny per-relation constants + attention-vector projections ----------
__global__ void k_small(const float* __restrict__ rel_emb, const float* __restrict__ W_relT,
                        const float* __restrict__ W_relprop, const float* __restrict__ b_relprop,
                        const float* __restrict__ W_fuse, const float* __restrict__ W_src,
                        const float* __restrict__ b_src, const float* __restrict__ W_node,
                        const float* __restrict__ b_node,
                        float* __restrict__ relfeat, float* __restrict__ wes, float* __restrict__ wed,
                        float* __restrict__ ces, float* __restrict__ ced) {
    __shared__ float av[512];     // attn vectors [r][h][i][d]
    __shared__ float rp[2][128];  // rel_prop
    int t = threadIdx.x;  // 512 threads
    {
        int r = t >> 8, m = t & 255;
        float acc = 0.f;
        const float* re = rel_emb + r * 64;
        const float* w = W_relT + (size_t)r * 16384 + m;
        #pragma unroll 8
        for (int k = 0; k < 64; ++k) acc += re[k] * w[(size_t)k * 256];
        av[t] = acc;
    }
    if (t < 256) {
        int r = t >> 7, m = t & 127;
        float acc = b_relprop[t];
        const float* re = rel_emb + r * 64;
        const float* w = W_relprop + (size_t)r * 8192 + m;
        #pragma unroll 8
        for (int k = 0; k < 64; ++k) acc += re[k] * w[(size_t)k * 128];
        rp[r][m] = acc;
    }
    __syncthreads();
    if (t < 256) {  // relation fusing feature
        int r = t >> 7, h = (t >> 5) & 3, d = t & 31;
        float acc = 0.f;
        const float* w = W_fuse + ((size_t)(r * 4 + h) * 32) * 32 + d;
        #pragma unroll
        for (int k = 0; k < 32; ++k) acc += rp[r][h * 32 + k] * w[(size_t)k * 32];
        relfeat[t] = acc;
    }
    // project attn vectors through weights so edge scores come straight from x
    for (int idx = t; idx < 2048; idx += 512) {
        int which = idx >> 10, rem = idx & 1023;
        int r = rem >> 9, h = (rem >> 7) & 3, c = rem & 127;
        const float* W = which ? W_node : (W_src + (size_t)r * 16384);
        const float* a = av + r * 256 + h * 64 + which * 32;
        float acc = 0.f;
        #pragma unroll
        for (int d = 0; d < 32; ++d) acc += W[(size_t)c * 128 + h * 32 + d] * a[d];
        (which ? wed : wes)[rem] = acc;
    }
    if (t < 16) {
        int which = t >> 3, r = (t >> 2) & 1, h = t & 3;
        const float* b = which ? b_node : (b_src + r * 128);
        const float* a = av + r * 256 + h * 64 + which * 32;
        float acc = 0.f;
        #pragma unroll
        for (int d = 0; d < 32; ++d) acc += b[h * 32 + d] * a[d];
        (which ? ced : ces)[r * 4 + h] = acc;
    }
}

// ---------- CSR build, stage 1: coarse bucket counts (LDS hist, few global atomics) ----------
// jobs: 0 = dst rel0, 1 = dst rel1, 2 = src combined (both relations)
__global__ __launch_bounds__(256) void k_count(const int* __restrict__ src, const int* __restrict__ dst,
                                               int E, int RE, int* __restrict__ bucketTot) {
    int j = blockIdx.y;
    const int* keys; int len;
    if (j == 0)      { keys = dst;     len = E;  }
    else if (j == 1) { keys = dst + E; len = E;  }
    else             { keys = src;     len = RE; }
    __shared__ int hist[256];
    hist[threadIdx.x] = 0;
    __syncthreads();
    int chunk = (len + gridDim.x - 1) / gridDim.x;
    int lo = blockIdx.x * chunk, hi = min(lo + chunk, len);
    for (int i = lo + threadIdx.x; i < hi; i += 256)
        atomicAdd(&hist[keys[i] >> 9], 1);
    __syncthreads();
    int h = hist[threadIdx.x];
    if (h) atomicAdd(&bucketTot[j * 256 + threadIdx.x], h);
}

// ---------- stage 2: exclusive scan of bucket totals -> bases + scatter cursors ----------
__global__ __launch_bounds__(256) void k_bases(const int* __restrict__ bucketTot,
                                               int* __restrict__ bucketBase, int* __restrict__ cursor,
                                               int* __restrict__ ip0, int* __restrict__ ip1,
                                               int N, int E) {
    __shared__ int sc[256];
    int t = threadIdx.x;
    for (int j = 0; j < 3; ++j) {
        int v = bucketTot[j * 256 + t];
        sc[t] = v;
        __syncthreads();
        for (int off = 1; off < 256; off <<= 1) {
            int tmp = (t >= off) ? sc[t - off] : 0;
            __syncthreads();
            sc[t] += tmp;
            __syncthreads();
        }
        int excl = sc[t] - v;
        bucketBase[j * 257 + t] = excl;
        if (t == 255) bucketBase[j * 257 + 256] = sc[255];
        cursor[j * 256 + t] = excl;
        __syncthreads();
    }
    if (t == 0) { ip0[N] = E; ip1[N] = E; }
}

// ---------- stage 3: coarse scatter into bucket regions (LDS cursors, 1 reservation/bin/block) ----------
__global__ __launch_bounds__(256) void k_cscatter(const int* __restrict__ src, const int* __restrict__ dst,
                                                  int E, int RE, int* __restrict__ cursor,
                                                  uint2* __restrict__ pairs0, uint2* __restrict__ pairs1,
                                                  int* __restrict__ svals) {
    int j = blockIdx.y;
    const int* keys; const int* pay; int len;
    if (j == 0)      { keys = dst;     pay = src;     len = E;  }
    else if (j == 1) { keys = dst + E; pay = src + E; len = E;  }
    else             { keys = src;     pay = nullptr; len = RE; }
    __shared__ int hist[256];
    __shared__ int cur[256];
    hist[threadIdx.x] = 0;
    __syncthreads();
    int chunk = (len + gridDim.x - 1) / gridDim.x;
    int lo = blockIdx.x * chunk, hi = min(lo + chunk, len);
    for (int i = lo + threadIdx.x; i < hi; i += 256)
        atomicAdd(&hist[keys[i] >> 9], 1);
    __syncthreads();
    int h = hist[threadIdx.x];
    if (h) cur[threadIdx.x] = atomicAdd(&cursor[j * 256 + threadIdx.x], h);
    __syncthreads();
    if (j == 2) {
        for (int i = lo + threadIdx.x; i < hi; i += 256) {
            int k = keys[i];
            int pos = atomicAdd(&cur[k >> 9], 1);
            svals[pos] = k;
        }
    } else {
        uint2* pp = j ? pairs1 : pairs0;
        for (int i = lo + threadIdx.x; i < hi; i += 256) {
            int k = keys[i];
            int pos = atomicAdd(&cur[k >> 9], 1);
            pp[pos] = make_uint2((unsigned)pay[i], (unsigned)k);
        }
    }
}

// ---------- stage 4: per-bucket fine counting sort -> indptr + grouped srcs (all LDS) ----------
__global__ __launch_bounds__(512) void k_fine(const uint2* __restrict__ pairs0, const uint2* __restrict__ pairs1,
                                              const int* __restrict__ bucketBase,
                                              int* __restrict__ ip0, int* __restrict__ ip1,
                                              int* __restrict__ srcs0, int* __restrict__ srcs1, int N) {
    int r = blockIdx.y;
    const uint2* pairs = r ? pairs1 : pairs0;
    int* ip = r ? ip1 : ip0;
    int* srcs = r ? srcs1 : srcs0;
    int b = blockIdx.x;
    int ebase = bucketBase[r * 257 + b], eend = bucketBase[r * 257 + b + 1];
    __shared__ int hist[512];
    int t = threadIdx.x;
    hist[t] = 0;
    __syncthreads();
    for (int k = ebase + t; k < eend; k += 512)
        atomicAdd(&hist[pairs[k].y & 511], 1);
    __syncthreads();
    int v = hist[t];
    for (int off = 1; off < 512; off <<= 1) {
        int tmp = (t >= off) ? hist[t - off] : 0;
        __syncthreads();
        hist[t] += tmp;
        __syncthreads();
    }
    int excl = hist[t] - v;
    int node = (b << 9) + t;
    if (node < N) ip[node] = ebase + excl;
    __syncthreads();
    hist[t] = ebase + excl;  // reuse as scatter cursor
    __syncthreads();
    for (int k = ebase + t; k < eend; k += 512) {
        uint2 p = pairs[k];
        int pos = atomicAdd(&hist[p.y & 511], 1);
        srcs[pos] = (int)p.x;
    }
}

// ---------- stage 4b: per-bucket src out-degree histogram -> rsdo ----------
__global__ __launch_bounds__(512) void k_srcdeg(const int* __restrict__ svals, const int* __restrict__ bucketBase,
                                                float* __restrict__ rsdo, int N) {
    int b = blockIdx.x;
    int ebase = bucketBase[2 * 257 + b], eend = bucketBase[2 * 257 + b + 1];
    __shared__ int hist[512];
    int t = threadIdx.x;
    hist[t] = 0;
    __syncthreads();
    for (int k = ebase + t; k < eend; k += 512)
        atomicAdd(&hist[svals[k] & 511], 1);
    __syncthreads();
    int node = (b << 9) + t;
    if (node < N) rsdo[node] = rsqrtf(fmaxf((float)hist[t], 1.f));
}

// ---------- in-degree normalizer from indptr diffs ----------
__global__ void k_rs(const int* __restrict__ ip0, const int* __restrict__ ip1,
                     float* __restrict__ rsdi, int n) {
    int i = blockIdx.x * blockDim.x + threadIdx.x;
    if (i < n) {
        int c = (ip0[i + 1] - ip0[i]) + (ip1[i + 1] - ip1[i]);
        rsdi[i] = rsqrtf(fmaxf((float)c, 1.f));
    }
}

// ---------- both relations' feat_src GEMMs -> packed bf16 (x read once) ----------
__global__ __launch_bounds__(256) void k_gemm2(const float* __restrict__ X, const float* __restrict__ W_src,
                                               const float* __restrict__ b_src,
                                               unsigned int* __restrict__ fs0p, unsigned int* __restrict__ fs1p,
                                               int n) {
    __shared__ float xs[64 * 128];
    __shared__ float wc[32 * 128];
    int tid = threadIdx.x;
    int nb0 = blockIdx.x * 64;
    for (int i = tid; i < 64 * 32; i += 256) {
        int row = i >> 5, c4 = i & 31;
        float4 v = make_float4(0.f, 0.f, 0.f, 0.f);
        if (nb0 + row < n) v = *(const float4*)(X + (size_t)(nb0 + row) * 128 + c4 * 4);
        *(float4*)(xs + row * 128 + c4 * 4) = v;
    }
    int col4 = (tid & 31) * 4;
    int r0 = (tid >> 5) * 8;
    for (int rel = 0; rel < 2; ++rel) {
        const float* W = W_src + (size_t)rel * 16384;
        float acc[8][4];
        #pragma unroll
        for (int i = 0; i < 8; ++i)
            #pragma unroll
            for (int c = 0; c < 4; ++c) acc[i][c] = 0.f;
        for (int kc = 0; kc < 4; ++kc) {
            __syncthreads();
            for (int i = tid; i < 32 * 32; i += 256) {
                int kk = i >> 5, c4 = i & 31;
                *(float4*)(wc + kk * 128 + c4 * 4) = *(const float4*)(W + (size_t)(kc * 32 + kk) * 128 + c4 * 4);
            }
            __syncthreads();
            #pragma unroll
            for (int kk = 0; kk < 32; ++kk) {
                float4 w = *(const float4*)(wc + kk * 128 + col4);
                #pragma unroll
                for (int i = 0; i < 8; ++i) {
                    float xv = xs[(r0 + i) * 128 + kc * 32 + kk];
                    acc[i][0] += xv * w.x; acc[i][1] += xv * w.y;
                    acc[i][2] += xv * w.z; acc[i][3] += xv * w.w;
                }
            }
        }
        float4 b = *(const float4*)(b_src + rel * 128 + col4);
        unsigned int* fsp = rel ? fs1p : fs0p;
        #pragma unroll
        for (int i = 0; i < 8; ++i) {
            int row = nb0 + r0 + i;
            if (row < n) {
                uint2 w;
                w.x = bfpack(acc[i][0] + b.x, acc[i][1] + b.y);
                w.y = bfpack(acc[i][2] + b.z, acc[i][3] + b.w);
                *(uint2*)(fsp + (size_t)row * 64 + (col4 >> 1)) = w;
            }
        }
        __syncthreads();
    }
}

// ---------- per-node attention scores + xn = bf16(x * rsdo) ----------
__global__ __launch_bounds__(256) void k_nodescore(const float* __restrict__ x,
                                                   const float* __restrict__ rsdo,
                                                   const float* __restrict__ wes, const float* __restrict__ wed,
                                                   const float* __restrict__ ces, const float* __restrict__ ced,
                                                   float* __restrict__ es0, float* __restrict__ es1,
                                                   float* __restrict__ ed0, float* __restrict__ ed1,
                                                   unsigned int* __restrict__ xnp, int n) {
    __shared__ float xs[64 * 132];
    int tid = threadIdx.x;
    int nb0 = blockIdx.x * 64;
    for (int i = tid; i < 64 * 32; i += 256) {
        int row = i >> 5, c4 = i & 31;
        float4 v = make_float4(0.f, 0.f, 0.f, 0.f);
        if (nb0 + row < n) v = *(const float4*)(x + (size_t)(nb0 + row) * 128 + c4 * 4);
        *(float4*)(xs + row * 132 + c4 * 4) = v;
    }
    __syncthreads();
    for (int i = tid; i < 64 * 64; i += 256) {
        int row = i >> 6, c2 = i & 63;
        int gr = nb0 + row;
        if (gr < n) {
            float sc = rsdo[gr];
            xnp[(size_t)gr * 64 + c2] = bfpack(xs[row * 132 + 2 * c2] * sc, xs[row * 132 + 2 * c2 + 1] * sc);
        }
    }
    int node = tid >> 2;
    int gn = nb0 + node;
    if (gn >= n) return;
    #pragma unroll
    for (int q = 0; q < 4; ++q) {
        int j = (tid & 3) + q * 4;          // j = which*8 + r*4 + h
        int which = j >> 3, r = (j >> 2) & 1, h = j & 3;
        const float* w = (which ? wed : wes) + r * 512 + h * 128;
        float acc = (which ? ced : ces)[r * 4 + h];
        #pragma unroll 16
        for (int d = 0; d < 128; ++d) acc += xs[node * 132 + d] * w[d];
        float* outp = which ? (r ? ed1 : ed0) : (r ? es1 : es0);
        outp[(size_t)gn * 4 + h] = acc;
    }
}

// ---------- merged CSR gather-aggregate: one wave per node, both relations, fused fusion ----------
__global__ __launch_bounds__(256) void k_agg(const int* __restrict__ ip0, const int* __restrict__ srcs0,
                                             const int* __restrict__ ip1, const int* __restrict__ srcs1,
                                             const unsigned int* __restrict__ xnp,
                                             const unsigned int* __restrict__ fs0p, const unsigned int* __restrict__ fs1p,
                                             const float* __restrict__ es0, const float* __restrict__ es1,
                                             const float* __restrict__ ed0, const float* __restrict__ ed1,
                                             const float* __restrict__ relfeat,
                                             float* __restrict__ fbuf, float* __restrict__ hg, int n) {
    int node = blockIdx.x * 4 + (threadIdx.x >> 6);   // one 64-lane wave per node
    if (node >= n) return;
    int j2 = threadIdx.x & 63;                        // channel pair (2*j2, 2*j2+1)
    int h = j2 >> 4;
    float ed0v = ed0[(size_t)node * 4 + h];
    float ed1v = ed1[(size_t)node * 4 + h];
    float aU0x = 0.f, aU0y = 0.f, aU1x = 0.f, aU1y = 0.f, aHx = 0.f, aHy = 0.f;
    float s0 = 0.f, s1 = 0.f;
    int b0 = ip0[node], e0 = ip0[node + 1];
    #pragma unroll 2
    for (int k = b0; k < e0; ++k) {
        int s = srcs0[k];
        float ex = __expf(leaky(es0[(size_t)s * 4 + h] + ed0v));
        unsigned int fv = fs0p[(size_t)s * 64 + j2];
        unsigned int xv = xnp[(size_t)s * 64 + j2];
        aU0x += ex * bflo(fv); aU0y += ex * bfhi(fv);
        aHx += bflo(xv); aHy += bfhi(xv);
        s0 += ex;
    }
    int b1 = ip1[node], e1 = ip1[node + 1];
    #pragma unroll 2
    for (int k = b1; k < e1; ++k) {
        int s = srcs1[k];
        float ex = __expf(leaky(es1[(size_t)s * 4 + h] + ed1v));
        unsigned int fv = fs1p[(size_t)s * 64 + j2];
        unsigned int xv = xnp[(size_t)s * 64 + j2];
        aU1x += ex * bflo(fv); aU1y += ex * bfhi(fv);
        aHx += bflo(xv); aHy += bfhi(xv);
        s1 += ex;
    }
    float i0 = 1.f / (s0 + 1e-9f), i1 = 1.f / (s1 + 1e-9f);
    float f0x = fmaxf(aU0x * i0, 0.f), f0y = fmaxf(aU0y * i0, 0.f);
    float f1x = fmaxf(aU1x * i1, 0.f), f1y = fmaxf(aU1y * i1, 0.f);
    float sc0 = f0x * relfeat[2 * j2] + f0y * relfeat[2 * j2 + 1];
    float sc1 = f1x * relfeat[128 + 2 * j2] + f1y * relfeat[128 + 2 * j2 + 1];
    #pragma unroll
    for (int m = 1; m < 16; m <<= 1) {
        sc0 += __shfl_xor(sc0, m, 64);
        sc1 += __shfl_xor(sc1, m, 64);
    }
    sc0 = leaky(sc0); sc1 = leaky(sc1);
    float mx = fmaxf(sc0, sc1);
    float p0 = __expf(sc0 - mx), p1 = __expf(sc1 - mx);
    float inv = 1.f / (p0 + p1);
    p0 *= inv; p1 *= inv;
    float2 fu = make_float2(p0 * f0x + p1 * f1x, p0 * f0y + p1 * f1y);
    *(float2*)(fbuf + (size_t)node * 128 + 2 * j2) = fu;
    *(float2*)(hg + (size_t)node * 128 + 2 * j2) = make_float2(aHx, aHy);
}

// ---------- final: node_level GEMM (hg * rsdi @ W_g) + feat_dst GEMM (x @ W_node) + epilogue ----------
__global__ __launch_bounds__(256) void k_final(const float* __restrict__ x,
                                               const float* __restrict__ Wn, const float* __restrict__ bn,
                                               const float* __restrict__ Wg, const float* __restrict__ bg,
                                               const float* __restrict__ rsdi,
                                               const float* __restrict__ fused,
                                               const float* __restrict__ residual_w, const float* __restrict__ scale_w,
                                               float* __restrict__ out, int n) {
    __shared__ float xs[64 * 128];
    __shared__ float wc[32 * 128];
    int tid = threadIdx.x;
    int nb0 = blockIdx.x * 64;
    int col4 = (tid & 31) * 4;
    int r0 = (tid >> 5) * 8;
    float accg[8][4], accn[8][4];

    // ---- phase A: node_level pre-activation = (hg * rsdi) @ Wg ----
    for (int i = tid; i < 64 * 32; i += 256) {
        int row = i >> 5, c4 = i & 31;
        float4 v = make_float4(0.f, 0.f, 0.f, 0.f);
        if (nb0 + row < n) {
            float sc = rsdi[nb0 + row];
            v = *(const float4*)(out + (size_t)(nb0 + row) * 128 + c4 * 4);
            v.x *= sc; v.y *= sc; v.z *= sc; v.w *= sc;
        }
        *(float4*)(xs + row * 128 + c4 * 4) = v;
    }
    #pragma unroll
    for (int i = 0; i < 8; ++i)
        #pragma unroll
        for (int c = 0; c < 4; ++c) accg[i][c] = 0.f;
    for (int kc = 0; kc < 4; ++kc) {
        __syncthreads();
        for (int i = tid; i < 32 * 32; i += 256) {
            int kk = i >> 5, c4 = i & 31;
            *(float4*)(wc + kk * 128 + c4 * 4) = *(const float4*)(Wg + (size_t)(kc * 32 + kk) * 128 + c4 * 4);
        }
        __syncthreads();
        #pragma unroll
        for (int kk = 0; kk < 32; ++kk) {
            float4 w = *(const float4*)(wc + kk * 128 + col4);
            #pragma unroll
            for (int i = 0; i < 8; ++i) {
                float xv = xs[(r0 + i) * 128 + kc * 32 + kk];
                accg[i][0] += xv * w.x; accg[i][1] += xv * w.y;
                accg[i][2] += xv * w.z; accg[i][3] += xv * w.w;
            }
        }
    }
    __syncthreads();

    // ---- phase B: feat_dst pre-bias = x @ Wn ----
    for (int i = tid; i < 64 * 32; i += 256) {
        int row = i >> 5, c4 = i & 31;
        float4 v = make_float4(0.f, 0.f, 0.f, 0.f);
        if (nb0 + row < n) v = *(const float4*)(x + (size_t)(nb0 + row) * 128 + c4 * 4);
        *(float4*)(xs + row * 128 + c4 * 4) = v;
    }
    #pragma unroll
    for (int i = 0; i < 8; ++i)
        #pragma unroll
        for (int c = 0; c < 4; ++c) accn[i][c] = 0.f;
    for (int kc = 0; kc < 4; ++kc) {
        __syncthreads();
        for (int i = tid; i < 32 * 32; i += 256) {
            int kk = i >> 5, c4 = i & 31;
            *(float4*)(wc + kk * 128 + c4 * 4) = *(const float4*)(Wn + (size_t)(kc * 32 + kk) * 128 + c4 * 4);
        }
        __syncthreads();
        #pragma unroll
        for (int kk = 0; kk < 32; ++kk) {
            float4 w = *(const float4*)(wc + kk * 128 + col4);
            #pragma unroll
            for (int i = 0; i < 8; ++i) {
                float xv = xs[(r0 + i) * 128 + kc * 32 + kk];
                accn[i][0] += xv * w.x; accn[i][1] += xv * w.y;
                accn[i][2] += xv * w.z; accn[i][3] += xv * w.w;
            }
        }
    }

    // ---- epilogue ----
    float beta = 1.f / (1.f + __expf(-residual_w[0]));
    float av = 1.f / (1.f + __expf(-scale_w[0]));
    float4 bgv = *(const float4*)(bg + col4);
    float4 bnv = *(const float4*)(bn + col4);
    #pragma unroll
    for (int i = 0; i < 8; ++i) {
        int row = nb0 + r0 + i;
        if (row < n) {
            float4 fu4 = *(const float4*)(fused + (size_t)row * 128 + col4);
            float4 o;
            float fd, fu, nl;
            fd = accn[i][0] + bnv.x;
            fu = beta * fu4.x + (1.f - beta) * fd;
            nl = fmaxf(accg[i][0] + bgv.x, 0.f);
            o.x = av * fu + (1.f - av) * nl;
            fd = accn[i][1] + bnv.y;
            fu = beta * fu4.y + (1.f - beta) * fd;
            nl = fmaxf(accg[i][1] + bgv.y, 0.f);
            o.y = av * fu + (1.f - av) * nl;
            fd = accn[i][2] + bnv.z;
            fu = beta * fu4.z + (1.f - beta) * fd;
            nl = fmaxf(accg[i][2] + bgv.z, 0.f);
            o.z = av * fu + (1.f - av) * nl;
            fd = accn[i][3] + bnv.w;
            fu = beta * fu4.w + (1.f - beta) * fd;
            nl = fmaxf(accg[i][3] + bgv.w, 0.f);
            o.w = av * fu + (1.f - av) * nl;
            *(float4*)(out + (size_t)row * 128 + col4) = o;
        }
    }
}

extern "C" void kernel_launch(void* const* d_in, const int* in_sizes, int n_in,
                              void* d_out, int out_size, void* d_ws, size_t ws_size,
                              hipStream_t stream) {
    const float* x         = (const float*)d_in[0];
    const int*   src       = (const int*)d_in[1];
    const int*   dst       = (const int*)d_in[2];
    const float* rel_emb   = (const float*)d_in[3];
    const float* W_node    = (const float*)d_in[4];
    const float* b_node    = (const float*)d_in[5];
    const float* W_src     = (const float*)d_in[6];
    const float* b_src     = (const float*)d_in[7];
    const float* W_relT    = (const float*)d_in[8];
    const float* W_relprop = (const float*)d_in[9];
    const float* b_relprop = (const float*)d_in[10];
    const float* W_fuse    = (const float*)d_in[11];
    const float* resid_w   = (const float*)d_in[12];
    const float* scale_w   = (const float*)d_in[13];
    const float* W_g       = (const float*)d_in[14];
    const float* b_g       = (const float*)d_in[15];
    float* out = (float*)d_out;

    const int N = in_sizes[0] / 128;
    const int RE = in_sizes[1];
    const int E = RE / 2;
    const int NBUCK = (N + 511) >> 9;   // buckets of 512 nodes (<=256 for N<=131072)

    // workspace (~144 MB at N=1e5, E=1e6)
    float* ws = (float*)d_ws;
    size_t o = 0;
    float* fbuf = ws + o; o += (size_t)N * 128;   // fused features; aliased by pairs/svals earlier in the call
    unsigned int* fs0p = (unsigned int*)(ws + o); o += (size_t)N * 64;
    unsigned int* fs1p = (unsigned int*)(ws + o); o += (size_t)N * 64;
    unsigned int* xnp  = (unsigned int*)(ws + o); o += (size_t)N * 64;
    float* es0  = ws + o; o += (size_t)N * 4;
    float* es1  = ws + o; o += (size_t)N * 4;
    float* ed0  = ws + o; o += (size_t)N * 4;
    float* ed1  = ws + o; o += (size_t)N * 4;
    float* rsdo = ws + o; o += N;
    float* rsdi = ws + o; o += N;
    float* relfeat = ws + o; o += 256;
    float* wes  = ws + o; o += 1024;
    float* wed  = ws + o; o += 1024;
    float* ces  = ws + o; o += 16;
    float* ced  = ws + o; o += 16;
    int* ip0  = (int*)(ws + o); o += N + 1;
    int* ip1  = (int*)(ws + o); o += N + 1;
    int* srcs0 = (int*)(ws + o); o += E;
    int* srcs1 = (int*)(ws + o); o += E;
    int* bucketTot  = (int*)(ws + o); o += 768;
    int* bucketBase = (int*)(ws + o); o += 771;
    int* cursor     = (int*)(ws + o); o += 768;
    // transient sort scratch aliased into fbuf (dead until k_agg writes it)
    uint2* pairs0 = (uint2*)fbuf;                       // E * 8B
    uint2* pairs1 = (uint2*)((int*)fbuf + 2 * (size_t)E);
    int*   svals  = (int*)fbuf + 4 * (size_t)E;         // RE * 4B

    hipMemsetAsync(bucketTot, 0, 768 * sizeof(int), stream);

    k_small<<<1, 512, 0, stream>>>(rel_emb, W_relT, W_relprop, b_relprop, W_fuse,
                                   W_src, b_src, W_node, b_node,
                                   relfeat, wes, wed, ces, ced);
    dim3 cgrid(256, 3);
    k_count<<<cgrid, 256, 0, stream>>>(src, dst, E, RE, bucketTot);
    k_bases<<<1, 256, 0, stream>>>(bucketTot, bucketBase, cursor, ip0, ip1, N, E);
    k_cscatter<<<cgrid, 256, 0, stream>>>(src, dst, E, RE, cursor, pairs0, pairs1, svals);
    k_fine<<<dim3(NBUCK, 2), 512, 0, stream>>>(pairs0, pairs1, bucketBase, ip0, ip1, srcs0, srcs1, N);
    k_srcdeg<<<NBUCK, 512, 0, stream>>>(svals, bucketBase, rsdo, N);
    k_rs<<<(N + 255) / 256, 256, 0, stream>>>(ip0, ip1, rsdi, N);

    dim3 ggrid((N + 63) / 64);
    k_gemm2<<<ggrid, 256, 0, stream>>>(x, W_src, b_src, fs0p, fs1p, N);
    k_nodescore<<<ggrid, 256, 0, stream>>>(x, rsdo, wes, wed, ces, ced, es0, es1, ed0, ed1, xnp, N);

    k_agg<<<(N + 3) / 4, 256, 0, stream>>>(ip0, srcs0, ip1, srcs1, xnp, fs0p, fs1p,
                                           es0, es1, ed0, ed1, relfeat, fbuf, out, N);

    k_final<<<ggrid, 256, 0, stream>>>(x, W_node, b_node, W_g, b_g, rsdi,
                                       fbuf, resid_w, scale_w, out, N);
}

// Round 6
// 556.159 us; speedup vs baseline: 4.5499x; 1.2437x over previous
//
#include <hip/hip_runtime.h>
#include <cstddef>

#define NEG_SLOPE 0.2f

typedef __attribute__((ext_vector_type(8))) short bf16x8;
typedef __attribute__((ext_vector_type(4))) float f32x4;

__device__ __forceinline__ float leaky(float v) { return v >= 0.f ? v : NEG_SLOPE * v; }

// pack two f32 into two bf16 (RNE) in one uint: lo = a, hi = b
__device__ __forceinline__ unsigned int bfpack(float a, float b) {
    unsigned int ua = __float_as_uint(a);
    ua += 0x7fffu + ((ua >> 16) & 1u);
    unsigned int ub = __float_as_uint(b);
    ub += 0x7fffu + ((ub >> 16) & 1u);
    return (ua >> 16) | (ub & 0xffff0000u);
}
__device__ __forceinline__ float bflo(unsigned int u) { return __uint_as_float(u << 16); }
__device__ __forceinline__ float bfhi(unsigned int u) { return __uint_as_float(u & 0xffff0000u); }
__device__ __forceinline__ float bfs(unsigned short u) { return __uint_as_float(((unsigned int)u) << 16); }

// ---------- tiny per-relation constants + attention-vector projections ----------
__global__ void k_small(const float* __restrict__ rel_emb, const float* __restrict__ W_relT,
                        const float* __restrict__ W_relprop, const float* __restrict__ b_relprop,
                        const float* __restrict__ W_fuse, const float* __restrict__ W_src,
                        const float* __restrict__ b_src, const float* __restrict__ W_node,
                        const float* __restrict__ b_node,
                        float* __restrict__ relfeat, float* __restrict__ wes, float* __restrict__ wed,
                        float* __restrict__ ces, float* __restrict__ ced) {
    __shared__ float av[512];     // attn vectors [r][h][i][d]
    __shared__ float rp[2][128];  // rel_prop
    int t = threadIdx.x;  // 512 threads
    {
        int r = t >> 8, m = t & 255;
        float acc = 0.f;
        const float* re = rel_emb + r * 64;
        const float* w = W_relT + (size_t)r * 16384 + m;
        #pragma unroll 8
        for (int k = 0; k < 64; ++k) acc += re[k] * w[(size_t)k * 256];
        av[t] = acc;
    }
    if (t < 256) {
        int r = t >> 7, m = t & 127;
        float acc = b_relprop[t];
        const float* re = rel_emb + r * 64;
        const float* w = W_relprop + (size_t)r * 8192 + m;
        #pragma unroll 8
        for (int k = 0; k < 64; ++k) acc += re[k] * w[(size_t)k * 128];
        rp[r][m] = acc;
    }
    __syncthreads();
    if (t < 256) {  // relation fusing feature
        int r = t >> 7, h = (t >> 5) & 3, d = t & 31;
        float acc = 0.f;
        const float* w = W_fuse + ((size_t)(r * 4 + h) * 32) * 32 + d;
        #pragma unroll
        for (int k = 0; k < 32; ++k) acc += rp[r][h * 32 + k] * w[(size_t)k * 32];
        relfeat[t] = acc;
    }
    // project attn vectors through weights so edge scores come straight from x
    for (int idx = t; idx < 2048; idx += 512) {
        int which = idx >> 10, rem = idx & 1023;
        int r = rem >> 9, h = (rem >> 7) & 3, c = rem & 127;
        const float* W = which ? W_node : (W_src + (size_t)r * 16384);
        const float* a = av + r * 256 + h * 64 + which * 32;
        float acc = 0.f;
        #pragma unroll
        for (int d = 0; d < 32; ++d) acc += W[(size_t)c * 128 + h * 32 + d] * a[d];
        (which ? wed : wes)[rem] = acc;
    }
    if (t < 16) {
        int which = t >> 3, r = (t >> 2) & 1, h = t & 3;
        const float* b = which ? b_node : (b_src + r * 128);
        const float* a = av + r * 256 + h * 64 + which * 32;
        float acc = 0.f;
        #pragma unroll
        for (int d = 0; d < 32; ++d) acc += b[h * 32 + d] * a[d];
        (which ? ced : ces)[r * 4 + h] = acc;
    }
}

// ---------- transpose weights to bf16 W^T: wt[mat][n][k] = bf16(W[mat][k][n]) ----------
__global__ void k_twt(const float* __restrict__ Ws, const float* __restrict__ Wn,
                      const float* __restrict__ Wg, unsigned int* __restrict__ wt) {
    int idx = blockIdx.x * 256 + threadIdx.x;   // 4 * 128 * 64 = 32768 uints
    if (idx >= 32768) return;
    int mat = idx >> 13, rem = idx & 8191;
    int nrow = rem >> 6, kp = rem & 63;
    const float* W = mat < 2 ? Ws + (size_t)mat * 16384 : (mat == 2 ? Wn : Wg);
    wt[idx] = bfpack(W[(size_t)(2 * kp) * 128 + nrow], W[(size_t)(2 * kp + 1) * 128 + nrow]);
}

// ---------- CSR build, stage 1: coarse bucket counts ----------
__global__ __launch_bounds__(256) void k_count(const int* __restrict__ src, const int* __restrict__ dst,
                                               int E, int RE, int* __restrict__ bucketTot) {
    int j = blockIdx.y;
    const int* keys; int len;
    if (j == 0)      { keys = dst;     len = E;  }
    else if (j == 1) { keys = dst + E; len = E;  }
    else             { keys = src;     len = RE; }
    __shared__ int hist[256];
    hist[threadIdx.x] = 0;
    __syncthreads();
    int chunk = (len + gridDim.x - 1) / gridDim.x;
    int lo = blockIdx.x * chunk, hi = min(lo + chunk, len);
    for (int i = lo + threadIdx.x; i < hi; i += 256)
        atomicAdd(&hist[keys[i] >> 9], 1);
    __syncthreads();
    int h = hist[threadIdx.x];
    if (h) atomicAdd(&bucketTot[j * 256 + threadIdx.x], h);
}

// ---------- stage 2: scan bucket totals -> bases + cursors ----------
__global__ __launch_bounds__(256) void k_bases(const int* __restrict__ bucketTot,
                                               int* __restrict__ bucketBase, int* __restrict__ cursor,
                                               int* __restrict__ ip0, int* __restrict__ ip1,
                                               int N, int E) {
    __shared__ int sc[256];
    int t = threadIdx.x;
    for (int j = 0; j < 3; ++j) {
        int v = bucketTot[j * 256 + t];
        sc[t] = v;
        __syncthreads();
        for (int off = 1; off < 256; off <<= 1) {
            int tmp = (t >= off) ? sc[t - off] : 0;
            __syncthreads();
            sc[t] += tmp;
            __syncthreads();
        }
        int excl = sc[t] - v;
        bucketBase[j * 257 + t] = excl;
        if (t == 255) bucketBase[j * 257 + 256] = sc[255];
        cursor[j * 256 + t] = excl;
        __syncthreads();
    }
    if (t == 0) { ip0[N] = E; ip1[N] = E; }
}

// ---------- stage 3: coarse scatter into bucket regions ----------
__global__ __launch_bounds__(256) void k_cscatter(const int* __restrict__ src, const int* __restrict__ dst,
                                                  int E, int RE, int* __restrict__ cursor,
                                                  uint2* __restrict__ pairs0, uint2* __restrict__ pairs1,
                                                  int* __restrict__ svals) {
    int j = blockIdx.y;
    const int* keys; const int* pay; int len;
    if (j == 0)      { keys = dst;     pay = src;     len = E;  }
    else if (j == 1) { keys = dst + E; pay = src + E; len = E;  }
    else             { keys = src;     pay = nullptr; len = RE; }
    __shared__ int hist[256];
    __shared__ int cur[256];
    hist[threadIdx.x] = 0;
    __syncthreads();
    int chunk = (len + gridDim.x - 1) / gridDim.x;
    int lo = blockIdx.x * chunk, hi = min(lo + chunk, len);
    for (int i = lo + threadIdx.x; i < hi; i += 256)
        atomicAdd(&hist[keys[i] >> 9], 1);
    __syncthreads();
    int h = hist[threadIdx.x];
    if (h) cur[threadIdx.x] = atomicAdd(&cursor[j * 256 + threadIdx.x], h);
    __syncthreads();
    if (j == 2) {
        for (int i = lo + threadIdx.x; i < hi; i += 256) {
            int k = keys[i];
            int pos = atomicAdd(&cur[k >> 9], 1);
            svals[pos] = k;
        }
    } else {
        uint2* pp = j ? pairs1 : pairs0;
        for (int i = lo + threadIdx.x; i < hi; i += 256) {
            int k = keys[i];
            int pos = atomicAdd(&cur[k >> 9], 1);
            pp[pos] = make_uint2((unsigned)pay[i], (unsigned)k);
        }
    }
}

// ---------- stage 4: per-bucket fine counting sort -> indptr + grouped srcs ----------
__global__ __launch_bounds__(512) void k_fine(const uint2* __restrict__ pairs0, const uint2* __restrict__ pairs1,
                                              const int* __restrict__ bucketBase,
                                              int* __restrict__ ip0, int* __restrict__ ip1,
                                              int* __restrict__ srcs0, int* __restrict__ srcs1, int N) {
    int r = blockIdx.y;
    const uint2* pairs = r ? pairs1 : pairs0;
    int* ip = r ? ip1 : ip0;
    int* srcs = r ? srcs1 : srcs0;
    int b = blockIdx.x;
    int ebase = bucketBase[r * 257 + b], eend = bucketBase[r * 257 + b + 1];
    __shared__ int hist[512];
    int t = threadIdx.x;
    hist[t] = 0;
    __syncthreads();
    for (int k = ebase + t; k < eend; k += 512)
        atomicAdd(&hist[pairs[k].y & 511], 1);
    __syncthreads();
    int v = hist[t];
    for (int off = 1; off < 512; off <<= 1) {
        int tmp = (t >= off) ? hist[t - off] : 0;
        __syncthreads();
        hist[t] += tmp;
        __syncthreads();
    }
    int excl = hist[t] - v;
    int node = (b << 9) + t;
    if (node < N) ip[node] = ebase + excl;
    __syncthreads();
    hist[t] = ebase + excl;  // reuse as scatter cursor
    __syncthreads();
    for (int k = ebase + t; k < eend; k += 512) {
        uint2 p = pairs[k];
        int pos = atomicAdd(&hist[p.y & 511], 1);
        srcs[pos] = (int)p.x;
    }
}

// ---------- stage 4b: src out-degree histogram -> rsdo ----------
__global__ __launch_bounds__(512) void k_srcdeg(const int* __restrict__ svals, const int* __restrict__ bucketBase,
                                                float* __restrict__ rsdo, int N) {
    int b = blockIdx.x;
    int ebase = bucketBase[2 * 257 + b], eend = bucketBase[2 * 257 + b + 1];
    __shared__ int hist[512];
    int t = threadIdx.x;
    hist[t] = 0;
    __syncthreads();
    for (int k = ebase + t; k < eend; k += 512)
        atomicAdd(&hist[svals[k] & 511], 1);
    __syncthreads();
    int node = (b << 9) + t;
    if (node < N) rsdo[node] = rsqrtf(fmaxf((float)hist[t], 1.f));
}

// ---------- in-degree normalizer ----------
__global__ void k_rs(const int* __restrict__ ip0, const int* __restrict__ ip1,
                     float* __restrict__ rsdi, int n) {
    int i = blockIdx.x * blockDim.x + threadIdx.x;
    if (i < n) {
        int c = (ip0[i + 1] - ip0[i]) + (ip1[i + 1] - ip1[i]);
        rsdi[i] = rsqrtf(fmaxf((float)c, 1.f));
    }
}

// ---------- per-node attention scores + xb = bf16(x) ----------
__global__ __launch_bounds__(256) void k_prep(const float* __restrict__ x,
                                              const float* __restrict__ wes, const float* __restrict__ wed,
                                              const float* __restrict__ ces, const float* __restrict__ ced,
                                              float* __restrict__ es0, float* __restrict__ es1,
                                              float* __restrict__ ed0, float* __restrict__ ed1,
                                              unsigned int* __restrict__ xbp, int n) {
    __shared__ float xs[64 * 132];
    int tid = threadIdx.x;
    int nb0 = blockIdx.x * 64;
    for (int i = tid; i < 64 * 32; i += 256) {
        int row = i >> 5, c4 = i & 31;
        float4 v = make_float4(0.f, 0.f, 0.f, 0.f);
        if (nb0 + row < n) v = *(const float4*)(x + (size_t)(nb0 + row) * 128 + c4 * 4);
        *(float4*)(xs + row * 132 + c4 * 4) = v;
    }
    __syncthreads();
    for (int i = tid; i < 64 * 64; i += 256) {
        int row = i >> 6, c2 = i & 63;
        int gr = nb0 + row;
        if (gr < n)
            xbp[(size_t)gr * 64 + c2] = bfpack(xs[row * 132 + 2 * c2], xs[row * 132 + 2 * c2 + 1]);
    }
    int node = tid >> 2;
    int gn = nb0 + node;
    if (gn >= n) return;
    #pragma unroll
    for (int q = 0; q < 4; ++q) {
        int j = (tid & 3) + q * 4;          // j = which*8 + r*4 + h
        int which = j >> 3, r = (j >> 2) & 1, h = j & 3;
        const float* w = (which ? wed : wes) + r * 512 + h * 128;
        float acc = (which ? ced : ces)[r * 4 + h];
        #pragma unroll 16
        for (int d = 0; d < 128; ++d) acc += xs[node * 132 + d] * w[d];
        float* outp = which ? (r ? ed1 : ed0) : (r ? es1 : es0);
        outp[(size_t)gn * 4 + h] = acc;
    }
}

// ---------- MFMA GEMM: fs = bf16(xb @ W + b), 128-row tile, no LDS ----------
__global__ __launch_bounds__(256) void k_mm(const unsigned int* __restrict__ xbp,
                                            const unsigned short* __restrict__ wT,
                                            const float* __restrict__ bias,
                                            unsigned int* __restrict__ outp, int n) {
    int wid = threadIdx.x >> 6, lane = threadIdx.x & 63;
    int l15 = lane & 15, g = lane >> 4;
    int m0 = blockIdx.x * 128 + wid * 32;
    const unsigned short* Au = (const unsigned short*)xbp;
    f32x4 acc[2][8];
    #pragma unroll
    for (int mt = 0; mt < 2; ++mt)
        #pragma unroll
        for (int nt = 0; nt < 8; ++nt)
            #pragma unroll
            for (int r = 0; r < 4; ++r) acc[mt][nt][r] = 0.f;
    #pragma unroll
    for (int t = 0; t < 4; ++t) {
        bf16x8 a0 = *(const bf16x8*)(Au + (size_t)(m0 + l15) * 128 + t * 32 + g * 8);
        bf16x8 a1 = *(const bf16x8*)(Au + (size_t)(m0 + 16 + l15) * 128 + t * 32 + g * 8);
        #pragma unroll
        for (int nt = 0; nt < 8; ++nt) {
            bf16x8 b = *(const bf16x8*)(wT + (size_t)(nt * 16 + l15) * 128 + t * 32 + g * 8);
            acc[0][nt] = __builtin_amdgcn_mfma_f32_16x16x32_bf16(a0, b, acc[0][nt], 0, 0, 0);
            acc[1][nt] = __builtin_amdgcn_mfma_f32_16x16x32_bf16(a1, b, acc[1][nt], 0, 0, 0);
        }
    }
    #pragma unroll
    for (int mt = 0; mt < 2; ++mt)
        #pragma unroll
        for (int nt = 0; nt < 8; ++nt) {
            int col = nt * 16 + l15;
            float bv = bias[col];
            #pragma unroll
            for (int r = 0; r < 4; ++r) {
                int row = m0 + mt * 16 + g * 4 + r;
                float v = acc[mt][nt][r] + bv;
                float vp = __shfl_xor(v, 1);
                if (!(l15 & 1) && row < n)
                    outp[(size_t)row * 64 + (col >> 1)] = bfpack(v, vp);
            }
        }
}

// ---------- merged CSR gather-aggregate: one wave per node; bf16 outputs ----------
__global__ __launch_bounds__(256) void k_agg(const int* __restrict__ ip0, const int* __restrict__ srcs0,
                                             const int* __restrict__ ip1, const int* __restrict__ srcs1,
                                             const unsigned int* __restrict__ xbp,
                                             const unsigned int* __restrict__ fs0p, const unsigned int* __restrict__ fs1p,
                                             const float* __restrict__ es0, const float* __restrict__ es1,
                                             const float* __restrict__ ed0, const float* __restrict__ ed1,
                                             const float* __restrict__ rsdo, const float* __restrict__ rsdi,
                                             const float* __restrict__ relfeat,
                                             unsigned int* __restrict__ fubp, unsigned int* __restrict__ hgbp, int n) {
    int node = blockIdx.x * 4 + (threadIdx.x >> 6);   // one 64-lane wave per node
    if (node >= n) return;
    int j2 = threadIdx.x & 63;                        // channel pair (2*j2, 2*j2+1)
    int h = j2 >> 4;
    float ed0v = ed0[(size_t)node * 4 + h];
    float ed1v = ed1[(size_t)node * 4 + h];
    float aU0x = 0.f, aU0y = 0.f, aU1x = 0.f, aU1y = 0.f, aHx = 0.f, aHy = 0.f;
    float s0 = 0.f, s1 = 0.f;
    int b0 = ip0[node], e0 = ip0[node + 1];
    #pragma unroll 2
    for (int k = b0; k < e0; ++k) {
        int s = srcs0[k];
        float ex = __expf(leaky(es0[(size_t)s * 4 + h] + ed0v));
        unsigned int fv = fs0p[(size_t)s * 64 + j2];
        unsigned int xv = xbp[(size_t)s * 64 + j2];
        float rs = rsdo[s];
        aU0x += ex * bflo(fv); aU0y += ex * bfhi(fv);
        aHx += rs * bflo(xv); aHy += rs * bfhi(xv);
        s0 += ex;
    }
    int b1 = ip1[node], e1 = ip1[node + 1];
    #pragma unroll 2
    for (int k = b1; k < e1; ++k) {
        int s = srcs1[k];
        float ex = __expf(leaky(es1[(size_t)s * 4 + h] + ed1v));
        unsigned int fv = fs1p[(size_t)s * 64 + j2];
        unsigned int xv = xbp[(size_t)s * 64 + j2];
        float rs = rsdo[s];
        aU1x += ex * bflo(fv); aU1y += ex * bfhi(fv);
        aHx += rs * bflo(xv); aHy += rs * bfhi(xv);
        s1 += ex;
    }
    float i0 = 1.f / (s0 + 1e-9f), i1 = 1.f / (s1 + 1e-9f);
    float f0x = fmaxf(aU0x * i0, 0.f), f0y = fmaxf(aU0y * i0, 0.f);
    float f1x = fmaxf(aU1x * i1, 0.f), f1y = fmaxf(aU1y * i1, 0.f);
    float sc0 = f0x * relfeat[2 * j2] + f0y * relfeat[2 * j2 + 1];
    float sc1 = f1x * relfeat[128 + 2 * j2] + f1y * relfeat[128 + 2 * j2 + 1];
    #pragma unroll
    for (int m = 1; m < 16; m <<= 1) {
        sc0 += __shfl_xor(sc0, m, 64);
        sc1 += __shfl_xor(sc1, m, 64);
    }
    sc0 = leaky(sc0); sc1 = leaky(sc1);
    float mx = fmaxf(sc0, sc1);
    float p0 = __expf(sc0 - mx), p1 = __expf(sc1 - mx);
    float inv = 1.f / (p0 + p1);
    p0 *= inv; p1 *= inv;
    float rv = rsdi[node];
    fubp[(size_t)node * 64 + j2] = bfpack(p0 * f0x + p1 * f1x, p0 * f0y + p1 * f1y);
    hgbp[(size_t)node * 64 + j2] = bfpack(aHx * rv, aHy * rv);
}

// ---------- final: two MFMA GEMMs (hgb @ Wg, xb @ Wn) + fusion epilogue ----------
__global__ __launch_bounds__(256) void k_fin(const unsigned int* __restrict__ hgbp,
                                             const unsigned int* __restrict__ xbp,
                                             const unsigned short* __restrict__ wtg,
                                             const unsigned short* __restrict__ wtn,
                                             const float* __restrict__ bg, const float* __restrict__ bn,
                                             const unsigned int* __restrict__ fubp,
                                             const float* __restrict__ residual_w, const float* __restrict__ scale_w,
                                             float* __restrict__ out, int n) {
    int wid = threadIdx.x >> 6, lane = threadIdx.x & 63;
    int l15 = lane & 15, g = lane >> 4;
    int m0 = blockIdx.x * 128 + wid * 32;
    const unsigned short* Hu = (const unsigned short*)hgbp;
    const unsigned short* Xu = (const unsigned short*)xbp;
    const unsigned short* Fu = (const unsigned short*)fubp;
    f32x4 accn[2][8], accg[2][8];
    #pragma unroll
    for (int mt = 0; mt < 2; ++mt)
        #pragma unroll
        for (int nt = 0; nt < 8; ++nt)
            #pragma unroll
            for (int r = 0; r < 4; ++r) { accn[mt][nt][r] = 0.f; accg[mt][nt][r] = 0.f; }
    #pragma unroll
    for (int t = 0; t < 4; ++t) {
        bf16x8 a0 = *(const bf16x8*)(Xu + (size_t)(m0 + l15) * 128 + t * 32 + g * 8);
        bf16x8 a1 = *(const bf16x8*)(Xu + (size_t)(m0 + 16 + l15) * 128 + t * 32 + g * 8);
        #pragma unroll
        for (int nt = 0; nt < 8; ++nt) {
            bf16x8 b = *(const bf16x8*)(wtn + (size_t)(nt * 16 + l15) * 128 + t * 32 + g * 8);
            accn[0][nt] = __builtin_amdgcn_mfma_f32_16x16x32_bf16(a0, b, accn[0][nt], 0, 0, 0);
            accn[1][nt] = __builtin_amdgcn_mfma_f32_16x16x32_bf16(a1, b, accn[1][nt], 0, 0, 0);
        }
    }
    #pragma unroll
    for (int t = 0; t < 4; ++t) {
        bf16x8 a0 = *(const bf16x8*)(Hu + (size_t)(m0 + l15) * 128 + t * 32 + g * 8);
        bf16x8 a1 = *(const bf16x8*)(Hu + (size_t)(m0 + 16 + l15) * 128 + t * 32 + g * 8);
        #pragma unroll
        for (int nt = 0; nt < 8; ++nt) {
            bf16x8 b = *(const bf16x8*)(wtg + (size_t)(nt * 16 + l15) * 128 + t * 32 + g * 8);
            accg[0][nt] = __builtin_amdgcn_mfma_f32_16x16x32_bf16(a0, b, accg[0][nt], 0, 0, 0);
            accg[1][nt] = __builtin_amdgcn_mfma_f32_16x16x32_bf16(a1, b, accg[1][nt], 0, 0, 0);
        }
    }
    float beta = 1.f / (1.f + __expf(-residual_w[0]));
    float av = 1.f / (1.f + __expf(-scale_w[0]));
    #pragma unroll
    for (int mt = 0; mt < 2; ++mt)
        #pragma unroll
        for (int nt = 0; nt < 8; ++nt) {
            int col = nt * 16 + l15;
            float bnv = bn[col], bgv = bg[col];
            #pragma unroll
            for (int r = 0; r < 4; ++r) {
                int row = m0 + mt * 16 + g * 4 + r;
                if (row < n) {
                    float fu = bfs(Fu[(size_t)row * 128 + col]);
                    float fd = accn[mt][nt][r] + bnv;
                    float f = beta * fu + (1.f - beta) * fd;
                    float nl = fmaxf(accg[mt][nt][r] + bgv, 0.f);
                    out[(size_t)row * 128 + col] = av * f + (1.f - av) * nl;
                }
            }
        }
}

extern "C" void kernel_launch(void* const* d_in, const int* in_sizes, int n_in,
                              void* d_out, int out_size, void* d_ws, size_t ws_size,
                              hipStream_t stream) {
    const float* x         = (const float*)d_in[0];
    const int*   src       = (const int*)d_in[1];
    const int*   dst       = (const int*)d_in[2];
    const float* rel_emb   = (const float*)d_in[3];
    const float* W_node    = (const float*)d_in[4];
    const float* b_node    = (const float*)d_in[5];
    const float* W_src     = (const float*)d_in[6];
    const float* b_src     = (const float*)d_in[7];
    const float* W_relT    = (const float*)d_in[8];
    const float* W_relprop = (const float*)d_in[9];
    const float* b_relprop = (const float*)d_in[10];
    const float* W_fuse    = (const float*)d_in[11];
    const float* resid_w   = (const float*)d_in[12];
    const float* scale_w   = (const float*)d_in[13];
    const float* W_g       = (const float*)d_in[14];
    const float* b_g       = (const float*)d_in[15];
    float* out = (float*)d_out;

    const int N = in_sizes[0] / 128;
    const int RE = in_sizes[1];
    const int E = RE / 2;
    const int Npad = (N + 127) & ~127;
    const int NBUCK = (N + 511) >> 9;

    // workspace (~146 MB at N=1e5, E=1e6)
    float* ws = (float*)d_ws;
    size_t o = 0;
    unsigned int* fubp = (unsigned int*)(ws + o); o += (size_t)Npad * 64;  // fused bf16; aliased by sort scratch early
    unsigned int* xbp  = (unsigned int*)(ws + o); o += (size_t)Npad * 64;  // bf16 x
    unsigned int* fs0p = (unsigned int*)(ws + o); o += (size_t)Npad * 64;
    unsigned int* fs1p = (unsigned int*)(ws + o); o += (size_t)Npad * 64;
    unsigned int* hgbp = (unsigned int*)(ws + o); o += (size_t)Npad * 64;  // bf16 hg*rsdi
    float* es0  = ws + o; o += (size_t)N * 4;
    float* es1  = ws + o; o += (size_t)N * 4;
    float* ed0  = ws + o; o += (size_t)N * 4;
    float* ed1  = ws + o; o += (size_t)N * 4;
    float* rsdo = ws + o; o += N;
    float* rsdi = ws + o; o += N;
    unsigned int* wtu = (unsigned int*)(ws + o); o += 32768;  // bf16 W^T x4 mats
    float* relfeat = ws + o; o += 256;
    float* wes  = ws + o; o += 1024;
    float* wed  = ws + o; o += 1024;
    float* ces  = ws + o; o += 16;
    float* ced  = ws + o; o += 16;
    int* ip0  = (int*)(ws + o); o += N + 1;
    int* ip1  = (int*)(ws + o); o += N + 1;
    int* srcs0 = (int*)(ws + o); o += E;
    int* srcs1 = (int*)(ws + o); o += E;
    int* bucketTot  = (int*)(ws + o); o += 768;
    int* bucketBase = (int*)(ws + o); o += 771;
    int* cursor     = (int*)(ws + o); o += 768;
    // transient sort scratch aliased into fubp region (24 MB <= Npad*256B)
    uint2* pairs0 = (uint2*)fubp;
    uint2* pairs1 = pairs0 + (size_t)E;
    int*   svals  = (int*)(pairs1 + (size_t)E);

    const unsigned short* wts = (const unsigned short*)wtu;  // mat m at wts + m*16384

    hipMemsetAsync(bucketTot, 0, 768 * sizeof(int), stream);

    k_small<<<1, 512, 0, stream>>>(rel_emb, W_relT, W_relprop, b_relprop, W_fuse,
                                   W_src, b_src, W_node, b_node,
                                   relfeat, wes, wed, ces, ced);
    k_twt<<<128, 256, 0, stream>>>(W_src, W_node, W_g, wtu);
    dim3 cgrid(256, 3);
    k_count<<<cgrid, 256, 0, stream>>>(src, dst, E, RE, bucketTot);
    k_bases<<<1, 256, 0, stream>>>(bucketTot, bucketBase, cursor, ip0, ip1, N, E);
    k_cscatter<<<cgrid, 256, 0, stream>>>(src, dst, E, RE, cursor, pairs0, pairs1, svals);
    k_fine<<<dim3(NBUCK, 2), 512, 0, stream>>>(pairs0, pairs1, bucketBase, ip0, ip1, srcs0, srcs1, N);
    k_srcdeg<<<NBUCK, 512, 0, stream>>>(svals, bucketBase, rsdo, N);
    k_rs<<<(N + 255) / 256, 256, 0, stream>>>(ip0, ip1, rsdi, N);

    k_prep<<<(N + 63) / 64, 256, 0, stream>>>(x, wes, wed, ces, ced, es0, es1, ed0, ed1, xbp, N);

    k_mm<<<Npad / 128, 256, 0, stream>>>(xbp, wts, b_src, fs0p, N);
    k_mm<<<Npad / 128, 256, 0, stream>>>(xbp, wts + 16384, b_src + 128, fs1p, N);

    k_agg<<<(N + 3) / 4, 256, 0, stream>>>(ip0, srcs0, ip1, srcs1, xbp, fs0p, fs1p,
                                           es0, es1, ed0, ed1, rsdo, rsdi, relfeat, fubp, hgbp, N);

    k_fin<<<Npad / 128, 256, 0, stream>>>(hgbp, xbp, wts + 3 * 16384, wts + 2 * 16384,
                                          b_g, b_node, fubp, resid_w, scale_w, out, N);
}

// Round 9
// 534.387 us; speedup vs baseline: 4.7353x; 1.0407x over previous
//
#include <hip/hip_runtime.h>
#include <cstddef>

#define NEG_SLOPE 0.2f

typedef __attribute__((ext_vector_type(8))) short bf16x8;
typedef __attribute__((ext_vector_type(4))) float f32x4;

__device__ __forceinline__ float leaky(float v) { return v >= 0.f ? v : NEG_SLOPE * v; }

// pack two f32 into two bf16 (RNE) in one uint: lo = a, hi = b
__device__ __forceinline__ unsigned int bfpack(float a, float b) {
    unsigned int ua = __float_as_uint(a);
    ua += 0x7fffu + ((ua >> 16) & 1u);
    unsigned int ub = __float_as_uint(b);
    ub += 0x7fffu + ((ub >> 16) & 1u);
    return (ua >> 16) | (ub & 0xffff0000u);
}
__device__ __forceinline__ float bflo(unsigned int u) { return __uint_as_float(u << 16); }
__device__ __forceinline__ float bfhi(unsigned int u) { return __uint_as_float(u & 0xffff0000u); }
__device__ __forceinline__ float bfs(unsigned short u) { return __uint_as_float(((unsigned int)u) << 16); }

// ---------- tiny per-relation constants + attention-vector projections ----------
__global__ void k_small(const float* __restrict__ rel_emb, const float* __restrict__ W_relT,
                        const float* __restrict__ W_relprop, const float* __restrict__ b_relprop,
                        const float* __restrict__ W_fuse, const float* __restrict__ W_src,
                        const float* __restrict__ b_src, const float* __restrict__ W_node,
                        const float* __restrict__ b_node,
                        float* __restrict__ relfeat, float* __restrict__ wes, float* __restrict__ wed,
                        float* __restrict__ ces, float* __restrict__ ced) {
    __shared__ float av[512];     // attn vectors [r][h][i][d]
    __shared__ float rp[2][128];  // rel_prop
    int t = threadIdx.x;  // 512 threads
    {
        int r = t >> 8, m = t & 255;
        float acc = 0.f;
        const float* re = rel_emb + r * 64;
        const float* w = W_relT + (size_t)r * 16384 + m;
        #pragma unroll 8
        for (int k = 0; k < 64; ++k) acc += re[k] * w[(size_t)k * 256];
        av[t] = acc;
    }
    if (t < 256) {
        int r = t >> 7, m = t & 127;
        float acc = b_relprop[t];
        const float* re = rel_emb + r * 64;
        const float* w = W_relprop + (size_t)r * 8192 + m;
        #pragma unroll 8
        for (int k = 0; k < 64; ++k) acc += re[k] * w[(size_t)k * 128];
        rp[r][m] = acc;
    }
    __syncthreads();
    if (t < 256) {  // relation fusing feature
        int r = t >> 7, h = (t >> 5) & 3, d = t & 31;
        float acc = 0.f;
        const float* w = W_fuse + ((size_t)(r * 4 + h) * 32) * 32 + d;
        #pragma unroll
        for (int k = 0; k < 32; ++k) acc += rp[r][h * 32 + k] * w[(size_t)k * 32];
        relfeat[t] = acc;
    }
    // project attn vectors through weights so edge scores come straight from x
    for (int idx = t; idx < 2048; idx += 512) {
        int which = idx >> 10, rem = idx & 1023;
        int r = rem >> 9, h = (rem >> 7) & 3, c = rem & 127;
        const float* W = which ? W_node : (W_src + (size_t)r * 16384);
        const float* a = av + r * 256 + h * 64 + which * 32;
        float acc = 0.f;
        #pragma unroll
        for (int d = 0; d < 32; ++d) acc += W[(size_t)c * 128 + h * 32 + d] * a[d];
        (which ? wed : wes)[rem] = acc;
    }
    if (t < 16) {
        int which = t >> 3, r = (t >> 2) & 1, h = t & 3;
        const float* b = which ? b_node : (b_src + r * 128);
        const float* a = av + r * 256 + h * 64 + which * 32;
        float acc = 0.f;
        #pragma unroll
        for (int d = 0; d < 32; ++d) acc += b[h * 32 + d] * a[d];
        (which ? ced : ces)[r * 4 + h] = acc;
    }
}

// ---------- transpose weights to bf16 W^T: wt[mat][n][k] = bf16(W[mat][k][n]) ----------
__global__ void k_twt(const float* __restrict__ Ws, const float* __restrict__ Wn,
                      const float* __restrict__ Wg, unsigned int* __restrict__ wt) {
    int idx = blockIdx.x * 256 + threadIdx.x;   // 4 * 128 * 64 = 32768 uints
    if (idx >= 32768) return;
    int mat = idx >> 13, rem = idx & 8191;
    int nrow = rem >> 6, kp = rem & 63;
    const float* W = mat < 2 ? Ws + (size_t)mat * 16384 : (mat == 2 ? Wn : Wg);
    wt[idx] = bfpack(W[(size_t)(2 * kp) * 128 + nrow], W[(size_t)(2 * kp + 1) * 128 + nrow]);
}

// ---------- CSR build, stage 1: coarse bucket counts ----------
__global__ __launch_bounds__(256) void k_count(const int* __restrict__ src, const int* __restrict__ dst,
                                               int E, int RE, int* __restrict__ bucketTot) {
    int j = blockIdx.y;
    const int* keys; int len;
    if (j == 0)      { keys = dst;     len = E;  }
    else if (j == 1) { keys = dst + E; len = E;  }
    else             { keys = src;     len = RE; }
    __shared__ int hist[256];
    hist[threadIdx.x] = 0;
    __syncthreads();
    int chunk = (len + gridDim.x - 1) / gridDim.x;
    int lo = blockIdx.x * chunk, hi = min(lo + chunk, len);
    for (int i = lo + threadIdx.x; i < hi; i += 256)
        atomicAdd(&hist[keys[i] >> 9], 1);
    __syncthreads();
    int h = hist[threadIdx.x];
    if (h) atomicAdd(&bucketTot[j * 256 + threadIdx.x], h);
}

// ---------- stage 2: scan bucket totals -> bases + cursors ----------
__global__ __launch_bounds__(256) void k_bases(const int* __restrict__ bucketTot,
                                               int* __restrict__ bucketBase, int* __restrict__ cursor,
                                               int* __restrict__ ip0, int* __restrict__ ip1,
                                               int N, int E) {
    __shared__ int sc[256];
    int t = threadIdx.x;
    for (int j = 0; j < 3; ++j) {
        int v = bucketTot[j * 256 + t];
        sc[t] = v;
        __syncthreads();
        for (int off = 1; off < 256; off <<= 1) {
            int tmp = (t >= off) ? sc[t - off] : 0;
            __syncthreads();
            sc[t] += tmp;
            __syncthreads();
        }
        int excl = sc[t] - v;
        bucketBase[j * 257 + t] = excl;
        if (t == 255) bucketBase[j * 257 + 256] = sc[255];
        cursor[j * 256 + t] = excl;
        __syncthreads();
    }
    if (t == 0) { ip0[N] = E; ip1[N] = E; }
}

// ---------- stage 3: coarse scatter into bucket regions ----------
__global__ __launch_bounds__(256) void k_cscatter(const int* __restrict__ src, const int* __restrict__ dst,
                                                  int E, int RE, int* __restrict__ cursor,
                                                  uint2* __restrict__ pairs0, uint2* __restrict__ pairs1,
                                                  int* __restrict__ svals) {
    int j = blockIdx.y;
    const int* keys; const int* pay; int len;
    if (j == 0)      { keys = dst;     pay = src;     len = E;  }
    else if (j == 1) { keys = dst + E; pay = src + E; len = E;  }
    else             { keys = src;     pay = nullptr; len = RE; }
    __shared__ int hist[256];
    __shared__ int cur[256];
    hist[threadIdx.x] = 0;
    __syncthreads();
    int chunk = (len + gridDim.x - 1) / gridDim.x;
    int lo = blockIdx.x * chunk, hi = min(lo + chunk, len);
    for (int i = lo + threadIdx.x; i < hi; i += 256)
        atomicAdd(&hist[keys[i] >> 9], 1);
    __syncthreads();
    int h = hist[threadIdx.x];
    if (h) cur[threadIdx.x] = atomicAdd(&cursor[j * 256 + threadIdx.x], h);
    __syncthreads();
    if (j == 2) {
        for (int i = lo + threadIdx.x; i < hi; i += 256) {
            int k = keys[i];
            int pos = atomicAdd(&cur[k >> 9], 1);
            svals[pos] = k;
        }
    } else {
        uint2* pp = j ? pairs1 : pairs0;
        for (int i = lo + threadIdx.x; i < hi; i += 256) {
            int k = keys[i];
            int pos = atomicAdd(&cur[k >> 9], 1);
            pp[pos] = make_uint2((unsigned)pay[i], (unsigned)k);
        }
    }
}

// ---------- stage 4 (3 jobs): per-bucket fine sort (r=0,1) + src out-degree -> rsdo (r=2) ----------
__global__ __launch_bounds__(512) void k_fine(const uint2* __restrict__ pairs0, const uint2* __restrict__ pairs1,
                                              const int* __restrict__ svals,
                                              const int* __restrict__ bucketBase,
                                              int* __restrict__ ip0, int* __restrict__ ip1,
                                              int* __restrict__ srcs0, int* __restrict__ srcs1,
                                              float* __restrict__ rsdo, int N) {
    int r = blockIdx.y;
    int b = blockIdx.x;
    __shared__ int hist[512];
    int t = threadIdx.x;
    hist[t] = 0;
    __syncthreads();
    if (r == 2) {   // src out-degree histogram
        int ebase = bucketBase[2 * 257 + b], eend = bucketBase[2 * 257 + b + 1];
        for (int k = ebase + t; k < eend; k += 512)
            atomicAdd(&hist[svals[k] & 511], 1);
        __syncthreads();
        int node = (b << 9) + t;
        if (node < N) rsdo[node] = rsqrtf(fmaxf((float)hist[t], 1.f));
        return;
    }
    const uint2* pairs = r ? pairs1 : pairs0;
    int* ip = r ? ip1 : ip0;
    int* srcs = r ? srcs1 : srcs0;
    int ebase = bucketBase[r * 257 + b], eend = bucketBase[r * 257 + b + 1];
    for (int k = ebase + t; k < eend; k += 512)
        atomicAdd(&hist[pairs[k].y & 511], 1);
    __syncthreads();
    int v = hist[t];
    for (int off = 1; off < 512; off <<= 1) {
        int tmp = (t >= off) ? hist[t - off] : 0;
        __syncthreads();
        hist[t] += tmp;
        __syncthreads();
    }
    int excl = hist[t] - v;
    int node = (b << 9) + t;
    if (node < N) ip[node] = ebase + excl;
    __syncthreads();
    hist[t] = ebase + excl;  // reuse as scatter cursor
    __syncthreads();
    for (int k = ebase + t; k < eend; k += 512) {
        uint2 p = pairs[k];
        int pos = atomicAdd(&hist[p.y & 511], 1);
        srcs[pos] = (int)p.x;
    }
}

// ---------- per-node attention scores + xb = bf16(x) ----------
__global__ __launch_bounds__(256) void k_prep(const float* __restrict__ x,
                                              const float* __restrict__ wes, const float* __restrict__ wed,
                                              const float* __restrict__ ces, const float* __restrict__ ced,
                                              float* __restrict__ es0, float* __restrict__ es1,
                                              float* __restrict__ ed0, float* __restrict__ ed1,
                                              unsigned int* __restrict__ xbp, int n) {
    __shared__ float xs[64 * 132];
    int tid = threadIdx.x;
    int nb0 = blockIdx.x * 64;
    for (int i = tid; i < 64 * 32; i += 256) {
        int row = i >> 5, c4 = i & 31;
        float4 v = make_float4(0.f, 0.f, 0.f, 0.f);
        if (nb0 + row < n) v = *(const float4*)(x + (size_t)(nb0 + row) * 128 + c4 * 4);
        *(float4*)(xs + row * 132 + c4 * 4) = v;
    }
    __syncthreads();
    for (int i = tid; i < 64 * 64; i += 256) {
        int row = i >> 6, c2 = i & 63;
        int gr = nb0 + row;
        if (gr < n)
            xbp[(size_t)gr * 64 + c2] = bfpack(xs[row * 132 + 2 * c2], xs[row * 132 + 2 * c2 + 1]);
    }
    int node = tid >> 2;
    int gn = nb0 + node;
    if (gn >= n) return;
    #pragma unroll
    for (int q = 0; q < 4; ++q) {
        int j = (tid & 3) + q * 4;          // j = which*8 + r*4 + h
        int which = j >> 3, r = (j >> 2) & 1, h = j & 3;
        const float* w = (which ? wed : wes) + r * 512 + h * 128;
        float acc = (which ? ced : ces)[r * 4 + h];
        #pragma unroll 16
        for (int d = 0; d < 128; ++d) acc += xs[node * 132 + d] * w[d];
        float* outp = which ? (r ? ed1 : ed0) : (r ? es1 : es0);
        outp[(size_t)gn * 4 + h] = acc;
    }
}

// ---------- MFMA GEMM per relation (blockIdx.y): fs_r = bf16(xb @ W_r + b_r), 128-row tile ----------
__global__ __launch_bounds__(256) void k_mm(const unsigned int* __restrict__ xbp,
                                            const unsigned short* __restrict__ wts,
                                            const float* __restrict__ b_src,
                                            unsigned int* __restrict__ fs0p, unsigned int* __restrict__ fs1p,
                                            int n) {
    int rel = blockIdx.y;
    const unsigned short* wT = wts + (size_t)rel * 16384;
    const float* bias = b_src + rel * 128;
    unsigned int* outp = rel ? fs1p : fs0p;
    int wid = threadIdx.x >> 6, lane = threadIdx.x & 63;
    int l15 = lane & 15, g = lane >> 4;
    int m0 = blockIdx.x * 128 + wid * 32;
    const unsigned short* Au = (const unsigned short*)xbp;
    f32x4 acc[2][8];
    #pragma unroll
    for (int mt = 0; mt < 2; ++mt)
        #pragma unroll
        for (int nt = 0; nt < 8; ++nt)
            #pragma unroll
            for (int r = 0; r < 4; ++r) acc[mt][nt][r] = 0.f;
    #pragma unroll
    for (int t = 0; t < 4; ++t) {
        bf16x8 a0 = *(const bf16x8*)(Au + (size_t)(m0 + l15) * 128 + t * 32 + g * 8);
        bf16x8 a1 = *(const bf16x8*)(Au + (size_t)(m0 + 16 + l15) * 128 + t * 32 + g * 8);
        #pragma unroll
        for (int nt = 0; nt < 8; ++nt) {
            bf16x8 b = *(const bf16x8*)(wT + (size_t)(nt * 16 + l15) * 128 + t * 32 + g * 8);
            acc[0][nt] = __builtin_amdgcn_mfma_f32_16x16x32_bf16(a0, b, acc[0][nt], 0, 0, 0);
            acc[1][nt] = __builtin_amdgcn_mfma_f32_16x16x32_bf16(a1, b, acc[1][nt], 0, 0, 0);
        }
    }
    #pragma unroll
    for (int mt = 0; mt < 2; ++mt)
        #pragma unroll
        for (int nt = 0; nt < 8; ++nt) {
            int col = nt * 16 + l15;
            float bv = bias[col];
            #pragma unroll
            for (int r = 0; r < 4; ++r) {
                int row = m0 + mt * 16 + g * 4 + r;
                float v = acc[mt][nt][r] + bv;
                float vp = __shfl_xor(v, 1);
                if (!(l15 & 1) && row < n)
                    outp[(size_t)row * 64 + (col >> 1)] = bfpack(v, vp);
            }
        }
}

// ---------- merged CSR gather-aggregate: one wave per node; fused relation softmax; bf16 outputs ----------
__global__ __launch_bounds__(256) void k_agg(const int* __restrict__ ip0, const int* __restrict__ srcs0,
                                             const int* __restrict__ ip1, const int* __restrict__ srcs1,
                                             const unsigned int* __restrict__ xbp,
                                             const unsigned int* __restrict__ fs0p, const unsigned int* __restrict__ fs1p,
                                             const float* __restrict__ es0, const float* __restrict__ es1,
                                             const float* __restrict__ ed0, const float* __restrict__ ed1,
                                             const float* __restrict__ rsdo,
                                             const float* __restrict__ relfeat,
                                             unsigned int* __restrict__ fubp, unsigned int* __restrict__ hgbp, int n) {
    int node = blockIdx.x * 4 + (threadIdx.x >> 6);   // one 64-lane wave per node
    if (node >= n) return;
    int j2 = threadIdx.x & 63;                        // channel pair (2*j2, 2*j2+1)
    int h = j2 >> 4;
    float ed0v = ed0[(size_t)node * 4 + h];
    float ed1v = ed1[(size_t)node * 4 + h];
    float aU0x = 0.f, aU0y = 0.f, aU1x = 0.f, aU1y = 0.f, aHx = 0.f, aHy = 0.f;
    float s0 = 0.f, s1 = 0.f;
    int b0 = ip0[node], e0 = ip0[node + 1];
    #pragma unroll 2
    for (int k = b0; k < e0; ++k) {
        int s = srcs0[k];
        float ex = __expf(leaky(es0[(size_t)s * 4 + h] + ed0v));
        unsigned int fv = fs0p[(size_t)s * 64 + j2];
        unsigned int xv = xbp[(size_t)s * 64 + j2];
        float rs = rsdo[s];
        aU0x += ex * bflo(fv); aU0y += ex * bfhi(fv);
        aHx += rs * bflo(xv); aHy += rs * bfhi(xv);
        s0 += ex;
    }
    int b1 = ip1[node], e1 = ip1[node + 1];
    #pragma unroll 2
    for (int k = b1; k < e1; ++k) {
        int s = srcs1[k];
        float ex = __expf(leaky(es1[(size_t)s * 4 + h] + ed1v));
        unsigned int fv = fs1p[(size_t)s * 64 + j2];
        unsigned int xv = xbp[(size_t)s * 64 + j2];
        float rs = rsdo[s];
        aU1x += ex * bflo(fv); aU1y += ex * bfhi(fv);
        aHx += rs * bflo(xv); aHy += rs * bfhi(xv);
        s1 += ex;
    }
    float i0 = 1.f / (s0 + 1e-9f), i1 = 1.f / (s1 + 1e-9f);
    float f0x = fmaxf(aU0x * i0, 0.f), f0y = fmaxf(aU0y * i0, 0.f);
    float f1x = fmaxf(aU1x * i1, 0.f), f1y = fmaxf(aU1y * i1, 0.f);
    float sc0 = f0x * relfeat[2 * j2] + f0y * relfeat[2 * j2 + 1];
    float sc1 = f1x * relfeat[128 + 2 * j2] + f1y * relfeat[128 + 2 * j2 + 1];
    #pragma unroll
    for (int m = 1; m < 16; m <<= 1) {
        sc0 += __shfl_xor(sc0, m, 64);
        sc1 += __shfl_xor(sc1, m, 64);
    }
    sc0 = leaky(sc0); sc1 = leaky(sc1);
    float mx = fmaxf(sc0, sc1);
    float p0 = __expf(sc0 - mx), p1 = __expf(sc1 - mx);
    float inv = 1.f / (p0 + p1);
    p0 *= inv; p1 *= inv;
    float rv = rsqrtf(fmaxf((float)((e0 - b0) + (e1 - b1)), 1.f));
    fubp[(size_t)node * 64 + j2] = bfpack(p0 * f0x + p1 * f1x, p0 * f0y + p1 * f1y);
    hgbp[(size_t)node * 64 + j2] = bfpack(aHx * rv, aHy * rv);
}

// ---------- final: two MFMA GEMMs (hgb @ Wg, xb @ Wn) + fusion epilogue ----------
__global__ __launch_bounds__(256) void k_fin(const unsigned int* __restrict__ hgbp,
                                             const unsigned int* __restrict__ xbp,
                                             const unsigned short* __restrict__ wtg,
                                             const unsigned short* __restrict__ wtn,
                                             const float* __restrict__ bg, const float* __restrict__ bn,
                                             const unsigned int* __restrict__ fubp,
                                             const float* __restrict__ residual_w, const float* __restrict__ scale_w,
                                             float* __restrict__ out, int n) {
    int wid = threadIdx.x >> 6, lane = threadIdx.x & 63;
    int l15 = lane & 15, g = lane >> 4;
    int m0 = blockIdx.x * 128 + wid * 32;
    const unsigned short* Hu = (const unsigned short*)hgbp;
    const unsigned short* Xu = (const unsigned short*)xbp;
    const unsigned short* Fu = (const unsigned short*)fubp;
    f32x4 accn[2][8], accg[2][8];
    #pragma unroll
    for (int mt = 0; mt < 2; ++mt)
        #pragma unroll
        for (int nt = 0; nt < 8; ++nt)
            #pragma unroll
            for (int r = 0; r < 4; ++r) { accn[mt][nt][r] = 0.f; accg[mt][nt][r] = 0.f; }
    #pragma unroll
    for (int t = 0; t < 4; ++t) {
        bf16x8 a0 = *(const bf16x8*)(Xu + (size_t)(m0 + l15) * 128 + t * 32 + g * 8);
        bf16x8 a1 = *(const bf16x8*)(Xu + (size_t)(m0 + 16 + l15) * 128 + t * 32 + g * 8);
        #pragma unroll
        for (int nt = 0; nt < 8; ++nt) {
            bf16x8 b = *(const bf16x8*)(wtn + (size_t)(nt * 16 + l15) * 128 + t * 32 + g * 8);
            accn[0][nt] = __builtin_amdgcn_mfma_f32_16x16x32_bf16(a0, b, accn[0][nt], 0, 0, 0);
            accn[1][nt] = __builtin_amdgcn_mfma_f32_16x16x32_bf16(a1, b, accn[1][nt], 0, 0, 0);
        }
    }
    #pragma unroll
    for (int t = 0; t < 4; ++t) {
        bf16x8 a0 = *(const bf16x8*)(Hu + (size_t)(m0 + l15) * 128 + t * 32 + g * 8);
        bf16x8 a1 = *(const bf16x8*)(Hu + (size_t)(m0 + 16 + l15) * 128 + t * 32 + g * 8);
        #pragma unroll
        for (int nt = 0; nt < 8; ++nt) {
            bf16x8 b = *(const bf16x8*)(wtg + (size_t)(nt * 16 + l15) * 128 + t * 32 + g * 8);
            accg[0][nt] = __builtin_amdgcn_mfma_f32_16x16x32_bf16(a0, b, accg[0][nt], 0, 0, 0);
            accg[1][nt] = __builtin_amdgcn_mfma_f32_16x16x32_bf16(a1, b, accg[1][nt], 0, 0, 0);
        }
    }
    float beta = 1.f / (1.f + __expf(-residual_w[0]));
    float av = 1.f / (1.f + __expf(-scale_w[0]));
    #pragma unroll
    for (int mt = 0; mt < 2; ++mt)
        #pragma unroll
        for (int nt = 0; nt < 8; ++nt) {
            int col = nt * 16 + l15;
            float bnv = bn[col], bgv = bg[col];
            #pragma unroll
            for (int r = 0; r < 4; ++r) {
                int row = m0 + mt * 16 + g * 4 + r;
                if (row < n) {
                    float fu = bfs(Fu[(size_t)row * 128 + col]);
                    float fd = accn[mt][nt][r] + bnv;
                    float f = beta * fu + (1.f - beta) * fd;
                    float nl = fmaxf(accg[mt][nt][r] + bgv, 0.f);
                    out[(size_t)row * 128 + col] = av * f + (1.f - av) * nl;
                }
            }
        }
}

extern "C" void kernel_launch(void* const* d_in, const int* in_sizes, int n_in,
                              void* d_out, int out_size, void* d_ws, size_t ws_size,
                              hipStream_t stream) {
    const float* x         = (const float*)d_in[0];
    const int*   src       = (const int*)d_in[1];
    const int*   dst       = (const int*)d_in[2];
    const float* rel_emb   = (const float*)d_in[3];
    const float* W_node    = (const float*)d_in[4];
    const float* b_node    = (const float*)d_in[5];
    const float* W_src     = (const float*)d_in[6];
    const float* b_src     = (const float*)d_in[7];
    const float* W_relT    = (const float*)d_in[8];
    const float* W_relprop = (const float*)d_in[9];
    const float* b_relprop = (const float*)d_in[10];
    const float* W_fuse    = (const float*)d_in[11];
    const float* resid_w   = (const float*)d_in[12];
    const float* scale_w   = (const float*)d_in[13];
    const float* W_g       = (const float*)d_in[14];
    const float* b_g       = (const float*)d_in[15];
    float* out = (float*)d_out;

    const int N = in_sizes[0] / 128;
    const int RE = in_sizes[1];
    const int E = RE / 2;
    const int Npad = (N + 127) & ~127;
    const int NBUCK = (N + 511) >> 9;

    // workspace (~146 MB at N=1e5, E=1e6)
    float* ws = (float*)d_ws;
    size_t o = 0;
    unsigned int* fubp = (unsigned int*)(ws + o); o += (size_t)Npad * 64;  // fused bf16; aliased by sort scratch early
    unsigned int* xbp  = (unsigned int*)(ws + o); o += (size_t)Npad * 64;  // bf16 x
    unsigned int* fs0p = (unsigned int*)(ws + o); o += (size_t)Npad * 64;
    unsigned int* fs1p = (unsigned int*)(ws + o); o += (size_t)Npad * 64;
    unsigned int* hgbp = (unsigned int*)(ws + o); o += (size_t)Npad * 64;  // bf16 hg*rsdi
    float* es0  = ws + o; o += (size_t)N * 4;
    float* es1  = ws + o; o += (size_t)N * 4;
    float* ed0  = ws + o; o += (size_t)N * 4;
    float* ed1  = ws + o; o += (size_t)N * 4;
    float* rsdo = ws + o; o += N;
    unsigned int* wtu = (unsigned int*)(ws + o); o += 32768;  // bf16 W^T x4 mats
    float* relfeat = ws + o; o += 256;
    float* wes  = ws + o; o += 1024;
    float* wed  = ws + o; o += 1024;
    float* ces  = ws + o; o += 16;
    float* ced  = ws + o; o += 16;
    int* ip0  = (int*)(ws + o); o += N + 1;
    int* ip1  = (int*)(ws + o); o += N + 1;
    int* srcs0 = (int*)(ws + o); o += E;
    int* srcs1 = (int*)(ws + o); o += E;
    int* bucketTot  = (int*)(ws + o); o += 768;
    int* bucketBase = (int*)(ws + o); o += 771;
    int* cursor     = (int*)(ws + o); o += 768;
    // transient sort scratch aliased into fubp region (24 MB <= Npad*256B)
    uint2* pairs0 = (uint2*)fubp;
    uint2* pairs1 = pairs0 + (size_t)E;
    int*   svals  = (int*)(pairs1 + (size_t)E);

    const unsigned short* wts = (const unsigned short*)wtu;  // mat m at wts + m*16384

    hipMemsetAsync(bucketTot, 0, 768 * sizeof(int), stream);

    k_small<<<1, 512, 0, stream>>>(rel_emb, W_relT, W_relprop, b_relprop, W_fuse,
                                   W_src, b_src, W_node, b_node,
                                   relfeat, wes, wed, ces, ced);
    k_twt<<<128, 256, 0, stream>>>(W_src, W_node, W_g, wtu);
    dim3 cgrid(256, 3);
    k_count<<<cgrid, 256, 0, stream>>>(src, dst, E, RE, bucketTot);
    k_bases<<<1, 256, 0, stream>>>(bucketTot, bucketBase, cursor, ip0, ip1, N, E);
    k_cscatter<<<cgrid, 256, 0, stream>>>(src, dst, E, RE, cursor, pairs0, pairs1, svals);
    k_fine<<<dim3(NBUCK, 3), 512, 0, stream>>>(pairs0, pairs1, svals, bucketBase,
                                               ip0, ip1, srcs0, srcs1, rsdo, N);

    k_prep<<<(N + 63) / 64, 256, 0, stream>>>(x, wes, wed, ces, ced, es0, es1, ed0, ed1, xbp, N);

    k_mm<<<dim3(Npad / 128, 2), 256, 0, stream>>>(xbp, wts, b_src, fs0p, fs1p, N);

    k_agg<<<(N + 3) / 4, 256, 0, stream>>>(ip0, srcs0, ip1, srcs1, xbp, fs0p, fs1p,
                                           es0, es1, ed0, ed1, rsdo, relfeat, fubp, hgbp, N);

    k_fin<<<Npad / 128, 256, 0, stream>>>(hgbp, xbp, wts + 3 * 16384, wts + 2 * 16384,
                                          b_g, b_node, fubp, resid_w, scale_w, out, N);
}